// Round 22
// baseline (901.761 us; speedup 1.0000x reference)
//
#include <hip/hip_runtime.h>
#include <math.h>
#include <stdint.h>
#include <stddef.h>

typedef unsigned short ushort_t;
typedef short  bf16x8 __attribute__((ext_vector_type(8)));
typedef float  f32x4  __attribute__((ext_vector_type(4)));
typedef unsigned short us4 __attribute__((ext_vector_type(4)));
typedef __bf16 bf16p2 __attribute__((ext_vector_type(2)));

// ---------------------------------------------------------------------------
static constexpr int NHEAD = 4;
static constexpr int HDIM  = 64;
static constexpr int HIDF  = 256;   // NHEAD*HDIM
static constexpr int OUTF  = 128;
static constexpr int N0 = 2048, N1 = 4096, N2 = 3072;   // participant, gene, metabolite
static constexpr int E_PG = 250000, E_GP = 250000, E_PM = 200000, E_MP = 200000;
static constexpr float ATT_SCALE = 0.125f;              // 1/sqrt(64)
static constexpr float LOG2E = 1.4426950408889634f;
static constexpr int EDGE_ITEMS = 2 * N0 + N1 + N2;     // 11264 (node,relation) items

enum { M_STORE = 0, M_ADD = 1, M_SKIP = 2, M_B16 = 3, M_GELU_B16 = 4,
       M_SPLITQ = 5, M_VT = 6, M_STOREBOTH = 7 };

__device__ __forceinline__ float gelu_exact(float x) {
    return 0.5f * x * (1.0f + erff(x * 0.7071067811865476f));
}
__device__ __forceinline__ ushort_t f2bf(float f) {       // RNE fp32->bf16
    unsigned x = __float_as_uint(f);
    return (ushort_t)((x + 0x7fffu + ((x >> 16) & 1u)) >> 16);
}
__device__ __forceinline__ float bflo(unsigned u) { return __uint_as_float(u << 16); }
__device__ __forceinline__ float bfhi(unsigned u) { return __uint_as_float(u & 0xffff0000u); }
__device__ __forceinline__ bf16p2 asbf2(unsigned u) { return __builtin_bit_cast(bf16p2, u); }

// ---------------------------------------------------------------------------
// MFMA GEMM v2: C = epilogue(A16[M,K] @ BT16[N,K]^T + bias). Runtime mode.
// Block = 128 rows x 64 cols; each wave owns 32 rows (2 A-frags) sharing the
// 4 B-frags -> 8 MFMA per 5 loads, with 1-step register prefetch.
struct MGemmDesc { const ushort_t* A; const ushort_t* BT; void* C;
                   const float* bias; const float* skipv; void* H;
                   int M; int K; int mode; float scale; };
template <int NZ> struct MGemmDescArr { MGemmDesc d[NZ]; };

template <int NZ>
__global__ __launch_bounds__(256) void gemm_mfma(MGemmDescArr<NZ> P, int N)
{
    const MGemmDesc g = P.d[blockIdx.z];
    const int bm = blockIdx.y << 7;            // 128 rows per block
    if (bm >= g.M) return;
    const int bn = blockIdx.x << 6;
    const int tid = threadIdx.x, wave = tid >> 6, lane = tid & 63;
    const int l15 = lane & 15, lg = lane >> 4;
    const int K = g.K;
    const ushort_t* arow = g.A + (size_t)(bm + (wave << 5) + l15) * K + (lg << 3);
    const ushort_t* brow = g.BT + (size_t)(bn + l15) * K + (lg << 3);

    f32x4 acc[2][4] = {};
    bf16x8 a0 = *(const bf16x8*)(arow);
    bf16x8 a1 = *(const bf16x8*)(arow + (size_t)16 * K);
    bf16x8 bv[4];
#pragma unroll
    for (int ct = 0; ct < 4; ct++)
        bv[ct] = *(const bf16x8*)(brow + (size_t)(ct << 4) * K);

    for (int k0 = 0; k0 < K; k0 += 32) {
        const bf16x8 ca0 = a0, ca1 = a1;
        bf16x8 cb[4];
#pragma unroll
        for (int ct = 0; ct < 4; ct++) cb[ct] = bv[ct];
        if (k0 + 32 < K) {
            a0 = *(const bf16x8*)(arow + k0 + 32);
            a1 = *(const bf16x8*)(arow + (size_t)16 * K + k0 + 32);
#pragma unroll
            for (int ct = 0; ct < 4; ct++)
                bv[ct] = *(const bf16x8*)(brow + (size_t)(ct << 4) * K + k0 + 32);
        }
#pragma unroll
        for (int ct = 0; ct < 4; ct++) {
            acc[0][ct] = __builtin_amdgcn_mfma_f32_16x16x32_bf16(ca0, cb[ct], acc[0][ct], 0, 0, 0);
            acc[1][ct] = __builtin_amdgcn_mfma_f32_16x16x32_bf16(ca1, cb[ct], acc[1][ct], 0, 0, 0);
        }
    }

    const int mode = g.mode;
    float gblend = 0.f, hblend = 0.f;
    if (mode == M_SKIP) {
        const float sv = g.skipv[0];
        gblend = 1.f / (1.f + expf(-sv));
        hblend = 1.f - gblend;
    }
#pragma unroll
    for (int g2 = 0; g2 < 2; g2++) {
        const int rbase = bm + (wave << 5) + (g2 << 4);
#pragma unroll
        for (int ct = 0; ct < 4; ct++) {
            const int col = bn + (ct << 4) + l15;
            const float bia = g.bias ? g.bias[col] : 0.f;
            if (mode == M_VT) {
                const int rowb = rbase + (lg << 2);
                us4 o;
#pragma unroll
                for (int r = 0; r < 4; r++) o[r] = f2bf(acc[g2][ct][r] + bia);
                *(us4*)((ushort_t*)g.C + (size_t)col * g.M + rowb) = o;
                continue;
            }
#pragma unroll
            for (int r = 0; r < 4; r++) {
                const int row = rbase + (lg << 2) + r;
                const float v = acc[g2][ct][r] + bia;
                if (mode == M_STORE) {
                    ((float*)g.C)[(size_t)row * N + col] = v;
                } else if (mode == M_ADD) {
                    ((float*)g.C)[(size_t)row * N + col] += v;
                } else if (mode == M_SKIP) {
                    ((float*)g.C)[(size_t)row * N + col] =
                        gblend * v + hblend * ((const float*)g.H)[(size_t)row * N + col];
                } else if (mode == M_B16) {
                    ((ushort_t*)g.C)[(size_t)row * N + col] = f2bf(v);
                } else if (mode == M_GELU_B16) {
                    ((ushort_t*)g.C)[(size_t)row * N + col] = f2bf(gelu_exact(v));
                } else if (mode == M_SPLITQ) {
                    ((ushort_t*)g.C)[((size_t)(col >> 6) * g.M + row) * 64 + (col & 63)]
                        = f2bf(v * g.scale);
                } else {
                    ((float*)g.C)[(size_t)row * N + col] = v;
                    ((ushort_t*)g.H)[(size_t)row * N + col] = f2bf(v);
                }
            }
        }
    }
}

// ---------------------------------------------------------------------------
// Weight transpose+cast: W[K][N] fp32 -> WT[N][K] bf16 (desc-batched).
struct TWDesc { const float* W; ushort_t* WT; int K; int N; };
template <int ND> struct TWDescArr { TWDesc d[ND]; };

template <int ND>
__global__ __launch_bounds__(256) void transW_kernel(TWDescArr<ND> P)
{
    const TWDesc g = P.d[blockIdx.z];
    const int k0 = blockIdx.x << 6, n0 = blockIdx.y << 6;
    if (k0 >= g.K || n0 >= g.N) return;
    __shared__ float Ls[64][65];
    const int tid = threadIdx.x, c = tid & 63, rq = tid >> 6;
    for (int rr = rq; rr < 64; rr += 4)
        Ls[rr][c] = g.W[(size_t)(k0 + rr) * g.N + n0 + c];
    __syncthreads();
    for (int nn = rq; nn < 64; nn += 4)
        g.WT[(size_t)(n0 + nn) * g.K + k0 + c] = f2bf(Ls[c][nn]);
}

// fp32 -> bf16 flat cast
__global__ void cast_bf16_kernel(const float* __restrict__ in, ushort_t* __restrict__ out, int n4)
{
    int i = blockIdx.x * 256 + threadIdx.x;
    if (i < n4) {
        float4 v = ((const float4*)in)[i];
        us4 o;
        o[0] = f2bf(v.x); o[1] = f2bf(v.y); o[2] = f2bf(v.z); o[3] = f2bf(v.w);
        *(us4*)(out + (size_t)i * 4) = o;
    }
}

// ---------------------------------------------------------------------------
// Fold a_rel into qw: W'T[(h*64+d)][k] = sum_f ar[h][d][f] * qw[k][h*64+f].
struct QFDesc { const float* ar; const float* qwm; const float* qbv;
                ushort_t* wT; float* bT; };
template <int ND> struct QFDescArr { QFDesc d[ND]; };

template <int ND>
__global__ __launch_bounds__(256) void qfold_kernel(QFDescArr<ND> P)
{
    const QFDesc g = P.d[blockIdx.y];
    const int h = blockIdx.x, tid = threadIdx.x;
    __shared__ float arS[64][64];   // [d][f]
    __shared__ float qbS[64];
    for (int i = tid; i < 4096; i += 256) arS[i >> 6][i & 63] = g.ar[(h << 12) + i];
    if (tid < 64) qbS[tid] = g.qbv[(h << 6) + tid];
    __syncthreads();
    float qv[64];
    const float* qrow = g.qwm + (size_t)tid * HIDF + (h << 6);
#pragma unroll
    for (int f = 0; f < 64; f++) qv[f] = qrow[f];
#pragma unroll 4
    for (int d = 0; d < 64; d++) {
        float a = 0.f;
#pragma unroll
        for (int f = 0; f < 64; f++) a = fmaf(arS[d][f], qv[f], a);
        g.wT[(size_t)((h << 6) + d) * HIDF + tid] = f2bf(a);
    }
    if (tid < 64) {
        float b = 0.f;
#pragma unroll
        for (int f = 0; f < 64; f++) b = fmaf(arS[tid][f], qbS[f], b);
        g.bT[(h << 6) + tid] = b;
    }
}

// ---------------------------------------------------------------------------
// Expand m_rel into block-diag bf16 W^T for the agg GEMM.
struct MXDesc { const float* A; const float* B; ushort_t* out; int Kc; };
template <int ND> struct MXDescArr { MXDesc d[ND]; };

template <int ND>
__global__ void mexpand_kernel(MXDescArr<ND> P)
{
    const MXDesc g = P.d[blockIdx.y];
    const int idx = blockIdx.x * 256 + threadIdx.x;
    if (idx >= 256 * g.Kc) return;
    const int col = idx / g.Kc, k = idx - col * g.Kc;
    const int h = col >> 6, f = col & 63;
    const float* M = g.A;
    int kd = k;
    if (k >= 256) { M = g.B; kd = k - 256; }
    const int hp = kd >> 6, d = kd & 63;
    const float v = (hp == h) ? M[(h << 12) + (d << 6) + f] : 0.f;
    g.out[idx] = f2bf(v);
}

// ---------------------------------------------------------------------------
// Counting sort by destination
__global__ void count_kernel(const int* __restrict__ dst, int E, int* __restrict__ cnt)
{
    int i = blockIdx.x * 256 + threadIdx.x;
    if (i < E) atomicAdd(&cnt[dst[i]], 1);
}

__global__ __launch_bounds__(256) void scan_kernel(int* __restrict__ cntcur, int N, int* __restrict__ off)
{
    __shared__ int sums[256];
    const int tid = threadIdx.x;
    const int base = tid * 16;
    int vals[16];
    int s = 0;
#pragma unroll
    for (int j = 0; j < 16; j++) {
        int idx = base + j;
        int c = (idx < N) ? cntcur[idx] : 0;
        vals[j] = s; s += c;
    }
    sums[tid] = s;
    __syncthreads();
    for (int d = 1; d < 256; d <<= 1) {
        int v = (tid >= d) ? sums[tid - d] : 0;
        __syncthreads();
        sums[tid] += v;
        __syncthreads();
    }
    int prefix = (tid > 0) ? sums[tid - 1] : 0;
#pragma unroll
    for (int j = 0; j < 16; j++) {
        int idx = base + j;
        if (idx < N) { int v = prefix + vals[j]; off[idx] = v; cntcur[idx] = v; }
    }
    if (tid == 255) off[N] = sums[255];
}

__global__ void scatter_kernel(const int* __restrict__ src, const int* __restrict__ dst, int E,
                               int* __restrict__ cur, int* __restrict__ esrc)
{
    int i = blockIdx.x * 256 + threadIdx.x;
    if (i < E) esrc[atomicAdd(&cur[dst[i]], 1)] = src[i];
}

// ---------------------------------------------------------------------------
// HGT edge attention core v9 — v6 structure (gathers, prefetch shadow,
// unconditional online softmax) with phase-1 dot on v_dot2_f32_bf16:
// 8 packed-dot ops replace 16 fma + 16 unpack per 16-dim slice.
__device__ __forceinline__ void edge_seg_v9(
    const bf16p2* __restrict__ qd,        // this lane's 16 Q' dims as 8 bf16 pairs
    float* __restrict__ sS,               // wave's 64-entry score LDS
    float2* __restrict__ wssh,            // wave's 64-entry {w,src} LDS
    const int* __restrict__ es, int i0, int i1,
    const ushort_t* __restrict__ Kt, const ushort_t* __restrict__ Vt,
    float pscale, int lane, int koff,
    float& m, float& plsum, float2& acc)
{
    if (i0 >= i1) return;
    const int seg = lane & 3, eidx = lane >> 2;
    const int epar = lane >> 5;
    const int dpair = (lane & 31) << 1;
    const int kbase_off = koff + (seg << 3);   // ushort offset of this lane's slice

    bool valid = (i0 + lane) < i1;
    int sidx = valid ? es[i0 + lane] : 0;
    uint4 kv[8];
#pragma unroll
    for (int p = 0; p < 4; p++) {
        const int sp = __shfl(sidx, (p << 4) + eidx);
        const ushort_t* kr = Kt + ((size_t)sp << 8) + kbase_off;
        kv[2 * p]     = *(const uint4*)(kr);
        kv[2 * p + 1] = *(const uint4*)(kr + 32);
    }

    for (int c = i0; c < i1; c += 64) {
        const int e2 = c + 64 + lane;
        const bool valid2 = e2 < i1;
        const int sidx2 = valid2 ? es[e2] : 0;

        // ---- phase 1: 16-dim partial dots via v_dot2_f32_bf16 ----
#pragma unroll
        for (int p = 0; p < 4; p++) {
            const uint4 k0 = kv[2 * p], k1 = kv[2 * p + 1];
            float dp = 0.f;
            dp = __builtin_amdgcn_fdot2_f32_bf16(asbf2(k0.x), qd[0], dp, false);
            dp = __builtin_amdgcn_fdot2_f32_bf16(asbf2(k0.y), qd[1], dp, false);
            dp = __builtin_amdgcn_fdot2_f32_bf16(asbf2(k0.z), qd[2], dp, false);
            dp = __builtin_amdgcn_fdot2_f32_bf16(asbf2(k0.w), qd[3], dp, false);
            dp = __builtin_amdgcn_fdot2_f32_bf16(asbf2(k1.x), qd[4], dp, false);
            dp = __builtin_amdgcn_fdot2_f32_bf16(asbf2(k1.y), qd[5], dp, false);
            dp = __builtin_amdgcn_fdot2_f32_bf16(asbf2(k1.z), qd[6], dp, false);
            dp = __builtin_amdgcn_fdot2_f32_bf16(asbf2(k1.w), qd[7], dp, false);
            dp += __shfl_xor(dp, 1);
            dp += __shfl_xor(dp, 2);
            if (seg == 0) sS[(p << 4) + eidx] = dp;
        }
        // ---- prefetch next chunk's K (latency hides under phases 2-3) ----
#pragma unroll
        for (int p = 0; p < 4; p++) {
            const int sp = __shfl(sidx2, (p << 4) + eidx);
            const ushort_t* kr = Kt + ((size_t)sp << 8) + kbase_off;
            kv[2 * p]     = *(const uint4*)(kr);
            kv[2 * p + 1] = *(const uint4*)(kr + 32);
        }

        const float a = valid ? sS[lane] * pscale : -INFINITY;

        // ---- phase 2: chunk max + online rescale ----
        float cm = a;
#pragma unroll
        for (int o = 32; o; o >>= 1) cm = fmaxf(cm, __shfl_xor(cm, o));
        const float mn = fmaxf(m, cm);
        const float sc = (m == -INFINITY) ? 0.f : expf(m - mn);
        const float w = valid ? expf(a - mn) : 0.f;
        plsum = plsum * sc + w;
        m = mn;
        wssh[lane] = make_float2(w, __int_as_float(sidx));

        // ---- phase 3: batched coalesced V accumulate ----
        acc.x *= sc; acc.y *= sc;
        float2 aE = make_float2(0.f, 0.f), aO = make_float2(0.f, 0.f);
#pragma unroll
        for (int b = 0; b < 64; b += 16) {
            float2 we[8];
            unsigned vv[8];
#pragma unroll
            for (int j = 0; j < 8; j++) we[j] = wssh[b + (j << 1) + epar];
#pragma unroll
            for (int j = 0; j < 8; j++) {
                const int sj = __float_as_int(we[j].y);
                vv[j] = *(const unsigned*)(Vt + (((size_t)sj) << 8) + koff + dpair);
            }
#pragma unroll
            for (int j = 0; j < 8; j++) {
                const float wj = we[j].x;
                if (j & 1) { aO.x = fmaf(wj, bflo(vv[j]), aO.x);
                             aO.y = fmaf(wj, bfhi(vv[j]), aO.y); }
                else       { aE.x = fmaf(wj, bflo(vv[j]), aE.x);
                             aE.y = fmaf(wj, bfhi(vv[j]), aE.y); }
            }
        }
        acc.x += aE.x + aO.x;
        acc.y += aE.y + aO.y;

        valid = valid2; sidx = sidx2;
    }
}

// ---------------------------------------------------------------------------
// Edge attention: ONE block per (node, relation) item — dispatch-order phase
// locality keeps each relation's K/V table hot in per-XCD L2 (grid-striding
// measured 2.6x more HBM fetch — round 14). 4 waves = 4 heads, NO barriers.
__global__ __launch_bounds__(256) void edge_attn_v9(
    const float* __restrict__ QpDA, const float* __restrict__ QpDB,
    const float* __restrict__ QpS1, const float* __restrict__ QpS2,
    const int* __restrict__ offGP, const int* __restrict__ esGP,
    const int* __restrict__ offMP, const int* __restrict__ esMP,
    const int* __restrict__ offPG, const int* __restrict__ esPG,
    const int* __restrict__ offPM, const int* __restrict__ esPM,
    const ushort_t* __restrict__ K0t, const ushort_t* __restrict__ V0t,
    const ushort_t* __restrict__ K1t, const ushort_t* __restrict__ V1t,
    const ushort_t* __restrict__ K2t, const ushort_t* __restrict__ V2t,
    const float* __restrict__ prel,
    float* __restrict__ accD, float* __restrict__ mlD,
    ushort_t* __restrict__ out1, ushort_t* __restrict__ out2)
{
    __shared__ float sS[NHEAD][64];
    __shared__ float2 wssh[NHEAD][64];
    const int b = blockIdx.x, tid = threadIdx.x, lane = tid & 63, h = tid >> 6;
    const int koff = h << 6, seg = lane & 3;

    const float* Qp; const int* off; const int* es;
    const ushort_t* Kt; const ushort_t* Vt;
    int node, r, dual = -1;
    if (b < N0)            { node = b;            Qp = QpDA; off = offGP; es = esGP; Kt = K1t; Vt = V1t; r = 1; dual = 0; }
    else if (b < 2 * N0)   { node = b - N0;       Qp = QpDB; off = offMP; es = esMP; Kt = K2t; Vt = V2t; r = 3; dual = 1; }
    else if (b < 2 * N0 + N1) { node = b - 2 * N0;      Qp = QpS1; off = offPG; es = esPG; Kt = K0t; Vt = V0t; r = 0; }
    else                      { node = b - 2 * N0 - N1; Qp = QpS2; off = offPM; es = esPM; Kt = K0t; Vt = V0t; r = 2; }

    const float* qrow = Qp + (size_t)node * HIDF + koff;
    float4 qv[4];
    qv[0] = *(const float4*)(qrow + (seg << 3));
    qv[1] = *(const float4*)(qrow + (seg << 3) + 4);
    qv[2] = *(const float4*)(qrow + 32 + (seg << 3));
    qv[3] = *(const float4*)(qrow + 32 + (seg << 3) + 4);
    bf16p2 qd[8];
#pragma unroll
    for (int i = 0; i < 4; i++) {
        const unsigned p0 = (unsigned)f2bf(qv[i].x) | ((unsigned)f2bf(qv[i].y) << 16);
        const unsigned p1 = (unsigned)f2bf(qv[i].z) | ((unsigned)f2bf(qv[i].w) << 16);
        qd[2 * i]     = asbf2(p0);
        qd[2 * i + 1] = asbf2(p1);
    }
    const float ps = prel[(r << 2) + h] * ATT_SCALE;
    float m = -INFINITY, plsum = 0.f;
    float2 acc = make_float2(0.f, 0.f);
    edge_seg_v9(qd, sS[h], wssh[h], es, off[node], off[node + 1],
                Kt, Vt, ps, lane, koff, m, plsum, acc);
    acc.x += __shfl_xor(acc.x, 32);
    acc.y += __shfl_xor(acc.y, 32);
    float l = plsum;
#pragma unroll
    for (int o = 32; o; o >>= 1) l += __shfl_xor(l, o);

    if (dual >= 0) {
        if (lane < 32)
            *(float2*)(accD + ((size_t)(dual * N0 + node)) * HIDF + koff + ((lane & 31) << 1))
                = acc;
        if (lane == 0) {
            mlD[((size_t)(dual * N0 + node)) * 8 + h * 2 + 0] = m;
            mlD[((size_t)(dual * N0 + node)) * 8 + h * 2 + 1] = l;
        }
    } else {
        const float inv = (l > 0.f) ? 1.f / l : 0.f;
        ushort_t* out = (r == 0) ? out1 : out2;
        if (lane < 32) {
            const unsigned pk = (unsigned)f2bf(acc.x * inv) | ((unsigned)f2bf(acc.y * inv) << 16);
            *(unsigned*)(out + (size_t)node * HIDF + koff + ((lane & 31) << 1)) = pk;
        }
    }
}

// Exact flash-combine of the two participant relations -> bf16 [N0][512].
__global__ __launch_bounds__(256) void combine0_kernel(
    const float* __restrict__ accD, const float* __restrict__ mlD,
    ushort_t* __restrict__ out0)
{
    const int node = blockIdx.x, col = threadIdx.x;   // col in [0,256)
    const int h = col >> 6;
    const float m0 = mlD[((size_t)node) * 8 + h * 2 + 0];
    const float l0 = mlD[((size_t)node) * 8 + h * 2 + 1];
    const float m1 = mlD[((size_t)(N0 + node)) * 8 + h * 2 + 0];
    const float l1 = mlD[((size_t)(N0 + node)) * 8 + h * 2 + 1];
    const float M = fmaxf(m0, m1);
    const float s0 = (m0 == -INFINITY) ? 0.f : expf(m0 - M);
    const float s1 = (m1 == -INFINITY) ? 0.f : expf(m1 - M);
    const float L = l0 * s0 + l1 * s1;
    const float f0 = (L > 0.f) ? s0 / L : 0.f;
    const float f1 = (L > 0.f) ? s1 / L : 0.f;
    const float a0 = accD[((size_t)node) * HIDF + col];
    const float a1 = accD[((size_t)(N0 + node)) * HIDF + col];
    out0[(size_t)node * 512 + col]       = f2bf(a0 * f0);
    out0[(size_t)node * 512 + 256 + col] = f2bf(a1 * f1);
}

// ---------------------------------------------------------------------------
// Flash cross-attention v3: 32 q-rows per block (two A fragments per wave,
// K/V registers reused across both -> 2x arithmetic intensity per K byte).
struct FlashDesc { const ushort_t* qh; const ushort_t* kh; const ushort_t* vT;
                   ushort_t* O; int Nq; };
template <int NF> struct FlashDescArr { FlashDesc d[NF]; };

template <int NF>
__global__ __launch_bounds__(256) void flash_ca(FlashDescArr<NF> P, int Nk)
{
    const FlashDesc g = P.d[blockIdx.z];
    const int q0 = blockIdx.x << 5;            // 32 q-rows per block
    if (q0 >= g.Nq) return;
    __shared__ float mS[4][32], lS[4][32];
    __shared__ __align__(16) char uS[18432];   // union: Pl[4][32][72] / oS[4][16][64]
    ushort_t (*Pl)[32][72] = (ushort_t (*)[32][72])uS;
    float    (*oS)[16][64] = (float (*)[16][64])uS;
    const int head = blockIdx.y;
    const int tid = threadIdx.x, wave = tid >> 6, lane = tid & 63;
    const int l15 = lane & 15, lg = lane >> 4;
    const int Nq = g.Nq;

    bf16x8 qa[2][2];
    {
        const ushort_t* qb0 = g.qh + ((size_t)head * Nq + q0 + l15) * 64 + (lg << 3);
        qa[0][0] = *(const bf16x8*)qb0;
        qa[0][1] = *(const bf16x8*)(qb0 + 32);
        qa[1][0] = *(const bf16x8*)(qb0 + 16 * 64);
        qa[1][1] = *(const bf16x8*)(qb0 + 16 * 64 + 32);
    }
    const ushort_t* kbase = g.kh + (size_t)head * Nk * 64;
    const ushort_t* vbase = g.vT + (size_t)head * 64 * Nk;
    const int kchunk = Nk >> 2;
    const int kbeg = wave * kchunk, kend = kbeg + kchunk;

    f32x4 o[2][4] = {};
    float m[2][4]     = {{-INFINITY,-INFINITY,-INFINITY,-INFINITY},
                         {-INFINITY,-INFINITY,-INFINITY,-INFINITY}};
    float plsum[2][4] = {};

    bf16x8 ka[8];
    {
        const ushort_t* krow = kbase + ((size_t)(kbeg + l15)) * 64 + (lg << 3);
#pragma unroll
        for (int ct = 0; ct < 4; ct++) {
            ka[ct]     = *(const bf16x8*)(krow + (ct << 10));
            ka[4 + ct] = *(const bf16x8*)(krow + (ct << 10) + 32);
        }
    }

    for (int k0 = kbeg; k0 < kend; k0 += 64) {
        bf16x8 vv[8];
        const ushort_t* vrow = vbase + (size_t)l15 * Nk + k0 + (lg << 3);
#pragma unroll
        for (int vt = 0; vt < 4; vt++) {
            vv[vt]     = *(const bf16x8*)(vrow + (size_t)(vt << 4) * Nk);
            vv[4 + vt] = *(const bf16x8*)(vrow + (size_t)(vt << 4) * Nk + 32);
        }
        f32x4 s[2][4] = {};
#pragma unroll
        for (int g2 = 0; g2 < 2; g2++)
#pragma unroll
            for (int ct = 0; ct < 4; ct++)
                s[g2][ct] = __builtin_amdgcn_mfma_f32_16x16x32_bf16(qa[g2][0], ka[ct], s[g2][ct], 0, 0, 0);
#pragma unroll
        for (int g2 = 0; g2 < 2; g2++)
#pragma unroll
            for (int ct = 0; ct < 4; ct++)
                s[g2][ct] = __builtin_amdgcn_mfma_f32_16x16x32_bf16(qa[g2][1], ka[4 + ct], s[g2][ct], 0, 0, 0);
        if (k0 + 64 < kend) {
            const ushort_t* krow2 = kbase + ((size_t)(k0 + 64 + l15)) * 64 + (lg << 3);
#pragma unroll
            for (int ct = 0; ct < 4; ct++) {
                ka[ct]     = *(const bf16x8*)(krow2 + (ct << 10));
                ka[4 + ct] = *(const bf16x8*)(krow2 + (ct << 10) + 32);
            }
        }
        float tm[2][4];
        bool need = false;
#pragma unroll
        for (int g2 = 0; g2 < 2; g2++)
#pragma unroll
            for (int r = 0; r < 4; r++) {
                tm[g2][r] = fmaxf(fmaxf(s[g2][0][r], s[g2][1][r]),
                                  fmaxf(s[g2][2][r], s[g2][3][r]));
                need = need || (tm[g2][r] > m[g2][r] + 11.54f);
            }
        if (__any(need)) {
#pragma unroll
            for (int off = 1; off <= 8; off <<= 1)
#pragma unroll
                for (int g2 = 0; g2 < 2; g2++)
#pragma unroll
                    for (int r = 0; r < 4; r++)
                        tm[g2][r] = fmaxf(tm[g2][r], __shfl_xor(tm[g2][r], off));
#pragma unroll
            for (int g2 = 0; g2 < 2; g2++)
#pragma unroll
                for (int r = 0; r < 4; r++) {
                    const float mn = fmaxf(m[g2][r], tm[g2][r]);
                    const float sc = exp2f(m[g2][r] - mn);
                    m[g2][r] = mn;
                    plsum[g2][r] *= sc;
#pragma unroll
                    for (int vt = 0; vt < 4; vt++) o[g2][vt][r] *= sc;
                }
        }
#pragma unroll
        for (int g2 = 0; g2 < 2; g2++)
#pragma unroll
            for (int ct = 0; ct < 4; ct++)
#pragma unroll
                for (int r = 0; r < 4; r++) {
                    const float p = exp2f(s[g2][ct][r] - m[g2][r]);
                    plsum[g2][r] += p;
                    Pl[wave][(g2 << 4) + (lg << 2) + r][(ct << 4) + l15] = f2bf(p);
                }
        const bf16x8 pa00 = *(const bf16x8*)&Pl[wave][l15][lg << 3];
        const bf16x8 pa01 = *(const bf16x8*)&Pl[wave][l15][32 + (lg << 3)];
        const bf16x8 pa10 = *(const bf16x8*)&Pl[wave][16 + l15][lg << 3];
        const bf16x8 pa11 = *(const bf16x8*)&Pl[wave][16 + l15][32 + (lg << 3)];
#pragma unroll
        for (int vt = 0; vt < 4; vt++) {
            o[0][vt] = __builtin_amdgcn_mfma_f32_16x16x32_bf16(pa00, vv[vt], o[0][vt], 0, 0, 0);
            o[1][vt] = __builtin_amdgcn_mfma_f32_16x16x32_bf16(pa10, vv[vt], o[1][vt], 0, 0, 0);
        }
#pragma unroll
        for (int vt = 0; vt < 4; vt++) {
            o[0][vt] = __builtin_amdgcn_mfma_f32_16x16x32_bf16(pa01, vv[4 + vt], o[0][vt], 0, 0, 0);
            o[1][vt] = __builtin_amdgcn_mfma_f32_16x16x32_bf16(pa11, vv[4 + vt], o[1][vt], 0, 0, 0);
        }
    }
#pragma unroll
    for (int off = 1; off <= 8; off <<= 1)
#pragma unroll
        for (int g2 = 0; g2 < 2; g2++)
#pragma unroll
            for (int r = 0; r < 4; r++)
                plsum[g2][r] += __shfl_xor(plsum[g2][r], off);
    if (l15 == 0) {
#pragma unroll
        for (int g2 = 0; g2 < 2; g2++)
#pragma unroll
            for (int r = 0; r < 4; r++) {
                mS[wave][(g2 << 4) + (lg << 2) + r] = m[g2][r];
                lS[wave][(g2 << 4) + (lg << 2) + r] = plsum[g2][r];
            }
    }
    __syncthreads();
#pragma unroll
    for (int g2 = 0; g2 < 2; g2++) {
        float fac[4];
#pragma unroll
        for (int r = 0; r < 4; r++) {
            const int grow = (g2 << 4) + (lg << 2) + r;
            const float ms = fmaxf(fmaxf(mS[0][grow], mS[1][grow]),
                                   fmaxf(mS[2][grow], mS[3][grow]));
            fac[r] = exp2f(m[g2][r] - ms);
        }
        __syncthreads();
#pragma unroll
        for (int vt = 0; vt < 4; vt++)
#pragma unroll
            for (int r = 0; r < 4; r++)
                oS[wave][(lg << 2) + r][(vt << 4) + l15] = o[g2][vt][r] * fac[r];
        __syncthreads();
        for (int i = tid; i < 1024; i += 256) {
            const int row = i >> 6, d = i & 63;
            const int grow = (g2 << 4) + row;
            const float m0 = mS[0][grow], m1 = mS[1][grow], m2 = mS[2][grow], m3 = mS[3][grow];
            const float ms = fmaxf(fmaxf(m0, m1), fmaxf(m2, m3));
            const float L = lS[0][grow] * exp2f(m0 - ms) + lS[1][grow] * exp2f(m1 - ms)
                          + lS[2][grow] * exp2f(m2 - ms) + lS[3][grow] * exp2f(m3 - ms);
            const float val = oS[0][row][d] + oS[1][row][d] + oS[2][row][d] + oS[3][row][d];
            g.O[(size_t)(q0 + grow) * HIDF + (head << 6) + d] = f2bf(val / L);
        }
    }
}

// ---------------------------------------------------------------------------
// Fused residual + LayerNorm + exact GELU over ALL node types in one launch.
__global__ __launch_bounds__(256) void ln_gelu_all(
    float* __restrict__ h, ushort_t* __restrict__ hb16, const float* __restrict__ hg,
    const float* __restrict__ lng, const float* __restrict__ lnb)
{
    __shared__ float t4[4];
    const int row = blockIdx.x, tid = threadIdx.x, lane = tid & 63, w = tid >> 6;
    const int t = (row >= N0) + (row >= N0 + N1);
    const size_t idx = (size_t)row * HIDF + tid;
    const float x = h[idx] + hg[idx];
    float v = x;
#pragma unroll
    for (int o = 32; o; o >>= 1) v += __shfl_xor(v, o);
    if (lane == 0) t4[w] = v;
    __syncthreads();
    const float mean = (t4[0] + t4[1] + t4[2] + t4[3]) * (1.f / 256.f);
    __syncthreads();
    const float d = x - mean;
    v = d * d;
#pragma unroll
    for (int o = 32; o; o >>= 1) v += __shfl_xor(v, o);
    if (lane == 0) t4[w] = v;
    __syncthreads();
    const float var = (t4[0] + t4[1] + t4[2] + t4[3]) * (1.f / 256.f);
    const float y = gelu_exact(d * rsqrtf(var + 1e-5f) * lng[t * HIDF + tid] + lnb[t * HIDF + tid]);
    h[idx] = y;
    hb16[idx] = f2bf(y);
}

// ---------------------------------------------------------------------------
extern "C" void kernel_launch(void* const* d_in, const int* in_sizes, int n_in,
                              void* d_out, int out_size, void* d_ws, size_t ws_size,
                              hipStream_t stream)
{
    (void)in_sizes; (void)n_in; (void)out_size; (void)ws_size;
    const float* x_p   = (const float*)d_in[0];
    const float* x_g   = (const float*)d_in[1];
    const float* x_m   = (const float*)d_in[2];
    const int*  src_pg = (const int*)d_in[3];
    const int*  dst_pg = (const int*)d_in[4];
    const int*  src_gp = (const int*)d_in[5];
    const int*  dst_gp = (const int*)d_in[6];
    const int*  src_pm = (const int*)d_in[7];
    const int*  dst_pm = (const int*)d_in[8];
    const int*  src_mp = (const int*)d_in[9];
    const int*  dst_mp = (const int*)d_in[10];
    const float* Win_p = (const float*)d_in[11];
    const float* bin_p = (const float*)d_in[12];
    const float* Win_g = (const float*)d_in[13];
    const float* bin_g = (const float*)d_in[14];
    const float* Win_m = (const float*)d_in[15];
    const float* bin_m = (const float*)d_in[16];
    const float* kw    = (const float*)d_in[17];
    const float* qw    = (const float*)d_in[18];
    const float* vw    = (const float*)d_in[19];
    const float* aw    = (const float*)d_in[20];
    const float* kb    = (const float*)d_in[21];
    const float* qb    = (const float*)d_in[22];
    const float* vb    = (const float*)d_in[23];
    const float* ab    = (const float*)d_in[24];
    const float* skip  = (const float*)d_in[25];
    const float* a_rel = (const float*)d_in[26];
    const float* m_rel = (const float*)d_in[27];
    const float* p_rel = (const float*)d_in[28];
    const float* ca_qw = (const float*)d_in[29];
    const float* ca_kw = (const float*)d_in[30];
    const float* ca_vw = (const float*)d_in[31];
    const float* ca_ow = (const float*)d_in[32];
    const float* ca_qb = (const float*)d_in[33];
    const float* ca_kb = (const float*)d_in[34];
    const float* ca_vb = (const float*)d_in[35];
    const float* ca_ob = (const float*)d_in[36];
    const float* ln_g  = (const float*)d_in[37];
    const float* ln_b  = (const float*)d_in[38];
    const float* outw  = (const float*)d_in[39];
    const float* outb  = (const float*)d_in[40];
    float* dout = (float*)d_out;

    // ---- workspace carve-up ----
    float* Wp = (float*)d_ws;
    size_t cursz = 0;
    auto alloc = [&](size_t n) -> float* {
        float* p = Wp + cursz; cursz += (n + 63) & ~(size_t)63; return p;
    };
    const size_t NT = N0 + N1 + N2;               // 9216
    float* h0  = alloc((size_t)N0 * HIDF);
    float* h1  = alloc((size_t)N1 * HIDF);
    float* h2  = alloc((size_t)N2 * HIDF);
    float* hg0 = alloc((size_t)N0 * HIDF);
    float* hg1 = alloc((size_t)N1 * HIDF);
    float* hg2 = alloc((size_t)N2 * HIDF);
    ushort_t* hb  = (ushort_t*)alloc(NT * HIDF / 2);
    ushort_t* K16 = (ushort_t*)alloc(NT * HIDF / 2);
    ushort_t* V16 = (ushort_t*)alloc(NT * HIDF / 2);
    ushort_t* K16_0 = K16, *K16_1 = K16 + (size_t)N0 * HIDF, *K16_2 = K16 + (size_t)(N0 + N1) * HIDF;
    ushort_t* V16_0 = V16, *V16_1 = V16 + (size_t)N0 * HIDF, *V16_2 = V16 + (size_t)(N0 + N1) * HIDF;
    float* QpPool  = alloc((size_t)(N1 + N0 + N2 + N0) * HIDF);   // fp32 Q' x4
    float* Qp0 = QpPool;
    float* Qp1 = Qp0 + (size_t)N1 * HIDF;
    float* Qp2 = Qp1 + (size_t)N0 * HIDF;
    float* Qp3 = Qp2 + (size_t)N2 * HIDF;
    float* accD = alloc((size_t)2 * N0 * HIDF);                   // dual fp32 partials
    float* mlD  = alloc((size_t)2 * N0 * 8);                      // dual (m,l) per head
    ushort_t* part0b = (ushort_t*)alloc((size_t)N0 * 512 / 2);    // [N0][512] bf16
    ushort_t* part1b = (ushort_t*)alloc((size_t)N1 * HIDF / 2);
    ushort_t* part2b = (ushort_t*)alloc((size_t)N2 * HIDF / 2);
    ushort_t* aggb16 = (ushort_t*)alloc(NT * HIDF / 2);
    ushort_t* qhA   = (ushort_t*)alloc((size_t)N1 * HIDF / 2);
    ushort_t* qhB   = (ushort_t*)alloc((size_t)N2 * HIDF / 2);
    ushort_t* khA   = (ushort_t*)alloc((size_t)N0 * HIDF / 2);
    ushort_t* khB   = (ushort_t*)alloc((size_t)N0 * HIDF / 2);
    ushort_t* vTA   = (ushort_t*)alloc((size_t)N0 * HIDF / 2);
    ushort_t* vTB   = (ushort_t*)alloc((size_t)N0 * HIDF / 2);
    ushort_t* caobA = (ushort_t*)alloc((size_t)N1 * HIDF / 2);
    ushort_t* caobB = (ushort_t*)alloc((size_t)N2 * HIDF / 2);
    ushort_t* WT16 = (ushort_t*)alloc(2621440 / 2);               // transposed weights
    ushort_t* WqpT = (ushort_t*)alloc((size_t)8 * 65536 / 2);     // folded Q' weights
    float*    bqp  = alloc(8 * 256);                              // folded Q' biases
    ushort_t* WmT  = (ushort_t*)alloc((size_t)2 * 262144 / 2);    // expanded m_rel
    // bf16 x inputs alias QpPool (dead before layer loop)
    ushort_t* xb = (ushort_t*)QpPool;
    const size_t xoff0 = 0, xoff1 = (size_t)N0 * 512, xoff2 = xoff1 + (size_t)N1 * 768;
    int* es_gp = (int*)alloc(E_GP);
    int* es_mp = (int*)alloc(E_MP);
    int* es_pg = (int*)alloc(E_PG);
    int* es_pm = (int*)alloc(E_PM);
    int* off_gp = (int*)alloc(N0 + 1); int* cur_gp = (int*)alloc(N0);
    int* off_mp = (int*)alloc(N0 + 1); int* cur_mp = (int*)alloc(N0);
    int* off_pg = (int*)alloc(N1 + 1); int* cur_pg = (int*)alloc(N1);
    int* off_pm = (int*)alloc(N2 + 1); int* cur_pm = (int*)alloc(N2);

    // WT16 sub-offsets (ushort units)
    ushort_t* kwT    = WT16;
    ushort_t* vwT    = WT16 + 6 * 65536;
    ushort_t* awT    = WT16 + 12 * 65536;
    ushort_t* ca_qwT = WT16 + 18 * 65536;
    ushort_t* ca_kwT = WT16 + 20 * 65536;
    ushort_t* ca_vwT = WT16 + 22 * 65536;
    ushort_t* ca_owT = WT16 + 24 * 65536;
    ushort_t* outwT  = WT16 + 26 * 65536;
    ushort_t* WinTp  = outwT + 3 * 32768;
    ushort_t* WinTg  = WinTp + 256 * 512;
    ushort_t* WinTm  = WinTg + 256 * 768;

    // ---- weight transpose+cast (32 matrices; qw folded separately) ----
    {
        TWDescArr<32> T;
        for (int i = 0; i < 6; i++) {
            T.d[i]      = { kw + (size_t)i * 65536, kwT + (size_t)i * 65536, 256, 256 };
            T.d[6 + i]  = { vw + (size_t)i * 65536, vwT + (size_t)i * 65536, 256, 256 };
            T.d[12 + i] = { aw + (size_t)i * 65536, awT + (size_t)i * 65536, 256, 256 };
        }
        for (int c = 0; c < 2; c++) {
            T.d[18 + c] = { ca_qw + (size_t)c * 65536, ca_qwT + (size_t)c * 65536, 256, 256 };
            T.d[20 + c] = { ca_kw + (size_t)c * 65536, ca_kwT + (size_t)c * 65536, 256, 256 };
            T.d[22 + c] = { ca_vw + (size_t)c * 65536, ca_vwT + (size_t)c * 65536, 256, 256 };
            T.d[24 + c] = { ca_ow + (size_t)c * 65536, ca_owT + (size_t)c * 65536, 256, 256 };
        }
        for (int t = 0; t < 3; t++)
            T.d[26 + t] = { outw + (size_t)t * 32768, outwT + (size_t)t * 32768, 256, 128 };
        T.d[29] = { Win_p, WinTp, 512, 256 };
        T.d[30] = { Win_g, WinTg, 768, 256 };
        T.d[31] = { Win_m, WinTm, 384, 256 };
        transW_kernel<32><<<dim3(12, 4, 32), 256, 0, stream>>>(T);
    }
    // ---- fold a_rel into qw (8 = L x 4 relations); dst(r) = {1,0,2,0} ----
    {
        const int dstt[4] = { 1, 0, 2, 0 };
        QFDescArr<8> Q;
        for (int l = 0; l < 2; l++)
            for (int r = 0; r < 4; r++) {
                const int z = l * 4 + r, dt = dstt[r];
                Q.d[z] = { a_rel + (size_t)z * 16384,
                           qw + (size_t)(l * 3 + dt) * 65536,
                           qb + (size_t)(l * 3 + dt) * 256,
                           WqpT + (size_t)z * 65536, bqp + (size_t)z * 256 };
            }
        qfold_kernel<8><<<dim3(NHEAD, 8), 256, 0, stream>>>(Q);
    }
    // ---- expand m_rel block-diag (per layer: dual K=512, singles K=256) ----
    ushort_t* WmT_l[2][3];
    {
        MXDescArr<6> X;
        for (int l = 0; l < 2; l++) {
            ushort_t* base = WmT + (size_t)l * 262144;
            WmT_l[l][0] = base;
            WmT_l[l][1] = base + 131072;
            WmT_l[l][2] = base + 196608;
            const float* mr = m_rel + (size_t)l * 4 * 16384;
            X.d[l * 3 + 0] = { mr + 1 * 16384, mr + 3 * 16384, WmT_l[l][0], 512 };
            X.d[l * 3 + 1] = { mr + 0 * 16384, nullptr,        WmT_l[l][1], 256 };
            X.d[l * 3 + 2] = { mr + 2 * 16384, nullptr,        WmT_l[l][2], 256 };
        }
        mexpand_kernel<6><<<dim3(512, 6), 256, 0, stream>>>(X);
    }

    // ---- counting-sort edges by destination (4 independent CSRs) ----
    hipMemsetAsync(cur_gp, 0, N0 * sizeof(int), stream);
    count_kernel<<<(E_GP + 255) / 256, 256, 0, stream>>>(dst_gp, E_GP, cur_gp);
    scan_kernel<<<1, 256, 0, stream>>>(cur_gp, N0, off_gp);
    scatter_kernel<<<(E_GP + 255) / 256, 256, 0, stream>>>(src_gp, dst_gp, E_GP, cur_gp, es_gp);

    hipMemsetAsync(cur_mp, 0, N0 * sizeof(int), stream);
    count_kernel<<<(E_MP + 255) / 256, 256, 0, stream>>>(dst_mp, E_MP, cur_mp);
    scan_kernel<<<1, 256, 0, stream>>>(cur_mp, N0, off_mp);
    scatter_kernel<<<(E_MP + 255) / 256, 256, 0, stream>>>(src_mp, dst_mp, E_MP, cur_mp, es_mp);

    hipMemsetAsync(cur_pg, 0, N1 * sizeof(int), stream);
    count_kernel<<<(E_PG + 255) / 256, 256, 0, stream>>>(dst_pg, E_PG, cur_pg);
    scan_kernel<<<1, 256, 0, stream>>>(cur_pg, N1, off_pg);
    scatter_kernel<<<(E_PG + 255) / 256, 256, 0, stream>>>(src_pg, dst_pg, E_PG, cur_pg, es_pg);

    hipMemsetAsync(cur_pm, 0, N2 * sizeof(int), stream);
    count_kernel<<<(E_PM + 255) / 256, 256, 0, stream>>>(dst_pm, E_PM, cur_pm);
    scan_kernel<<<1, 256, 0, stream>>>(cur_pm, N2, off_pm);
    scatter_kernel<<<(E_PM + 255) / 256, 256, 0, stream>>>(src_pm, dst_pm, E_PM, cur_pm, es_pm);

    float* hgptr[3] = { hg0, hg1, hg2 };
    float* hptr[3]  = { h0, h1, h2 };
    const int Ns[3] = { N0, N1, N2 };
    const size_t hoff[3] = { 0, (size_t)N0 * HIDF, (size_t)(N0 + N1) * HIDF };

    // ---- input projections (STOREBOTH: h fp32 + hb bf16) ----
    cast_bf16_kernel<<<(N0 * 512 / 4 + 255) / 256, 256, 0, stream>>>(x_p, xb + xoff0, N0 * 512 / 4);
    cast_bf16_kernel<<<(N1 * 768 / 4 + 255) / 256, 256, 0, stream>>>(x_g, xb + xoff1, N1 * 768 / 4);
    cast_bf16_kernel<<<(N2 * 384 / 4 + 255) / 256, 256, 0, stream>>>(x_m, xb + xoff2, N2 * 384 / 4);
    {
        MGemmDescArr<3> D;
        D.d[0] = { xb + xoff0, WinTp, h0, bin_p, nullptr, hb + hoff[0], N0, 512, M_STOREBOTH, 0.f };
        D.d[1] = { xb + xoff1, WinTg, h1, bin_g, nullptr, hb + hoff[1], N1, 768, M_STOREBOTH, 0.f };
        D.d[2] = { xb + xoff2, WinTm, h2, bin_m, nullptr, hb + hoff[2], N2, 384, M_STOREBOTH, 0.f };
        gemm_mfma<3><<<dim3(4, 32, 3), 256, 0, stream>>>(D, HIDF);
    }

    for (int l = 0; l < 2; l++) {
        // Q' (folded a_rel, x4) + K/V projections (x6) in ONE launch
        {
            ushort_t* Kp[3] = { K16_0, K16_1, K16_2 };
            ushort_t* Vp[3] = { V16_0, V16_1, V16_2 };
            const size_t zb = (size_t)l * 4;
            MGemmDescArr<10> D;
            D.d[0] = { hb + hoff[1], WqpT + (zb + 0) * 65536, Qp0, bqp + (zb + 0) * 256, nullptr, nullptr, N1, HIDF, M_STORE, 0.f };
            D.d[1] = { hb + hoff[0], WqpT + (zb + 1) * 65536, Qp1, bqp + (zb + 1) * 256, nullptr, nullptr, N0, HIDF, M_STORE, 0.f };
            D.d[2] = { hb + hoff[2], WqpT + (zb + 2) * 65536, Qp2, bqp + (zb + 2) * 256, nullptr, nullptr, N2, HIDF, M_STORE, 0.f };
            D.d[3] = { hb + hoff[0], WqpT + (zb + 3) * 65536, Qp3, bqp + (zb + 3) * 256, nullptr, nullptr, N0, HIDF, M_STORE, 0.f };
            for (int t = 0; t < 3; t++) {
                D.d[4 + t] = { hb + hoff[t], kwT + (size_t)(l * 3 + t) * 65536, Kp[t],
                               kb + (size_t)(l * 3 + t) * HIDF, nullptr, nullptr, Ns[t], HIDF, M_B16, 0.f };
                D.d[7 + t] = { hb + hoff[t], vwT + (size_t)(l * 3 + t) * 65536, Vp[t],
                               vb + (size_t)(l * 3 + t) * HIDF, nullptr, nullptr, Ns[t], HIDF, M_B16, 0.f };
            }
            gemm_mfma<10><<<dim3(4, 32, 10), 256, 0, stream>>>(D, HIDF);
        }
        // segment-softmax edge attention: one block per (node, relation)
        const float* prl = p_rel + (size_t)l * 16;
        edge_attn_v9<<<EDGE_ITEMS, 256, 0, stream>>>(
            Qp1, Qp3, Qp0, Qp2,
            off_gp, es_gp, off_mp, es_mp, off_pg, es_pg, off_pm, es_pm,
            K16_0, V16_0, K16_1, V16_1, K16_2, V16_2,
            prl, accD, mlD, part1b, part2b);
        combine0_kernel<<<N0, 256, 0, stream>>>(accD, mlD, part0b);
        // agg = gelu(sum_r partial_r @ m_rel[r]) -> bf16 (fused epilogue)
        {
            MGemmDescArr<3> D;
            D.d[0] = { part0b, WmT_l[l][0], aggb16 + hoff[0], nullptr, nullptr, nullptr, N0, 512, M_GELU_B16, 0.f };
            D.d[1] = { part1b, WmT_l[l][1], aggb16 + hoff[1], nullptr, nullptr, nullptr, N1, 256, M_GELU_B16, 0.f };
            D.d[2] = { part2b, WmT_l[l][2], aggb16 + hoff[2], nullptr, nullptr, nullptr, N2, 256, M_GELU_B16, 0.f };
            gemm_mfma<3><<<dim3(4, 32, 3), 256, 0, stream>>>(D, HIDF);
        }
        // hg-skip (x3) + CA projections (x6) in ONE launch (independent)
        {
            MGemmDescArr<9> D;
            for (int t = 0; t < 3; t++)
                D.d[t] = { aggb16 + hoff[t], awT + (size_t)(l * 3 + t) * 65536, hgptr[t],
                           ab + (size_t)(l * 3 + t) * HIDF, skip + l * 3 + t, hptr[t], Ns[t], HIDF, M_SKIP, 0.f };
            D.d[3] = { hb + hoff[1], ca_qwT + 0 * 65536, qhA, ca_qb + 0 * HIDF, nullptr, nullptr, N1, HIDF, M_SPLITQ, ATT_SCALE * LOG2E };
            D.d[4] = { hb + hoff[0], ca_kwT + 0 * 65536, khA, ca_kb + 0 * HIDF, nullptr, nullptr, N0, HIDF, M_SPLITQ, 1.0f };
            D.d[5] = { hb + hoff[0], ca_vwT + 0 * 65536, vTA, ca_vb + 0 * HIDF, nullptr, nullptr, N0, HIDF, M_VT, 0.f };
            D.d[6] = { hb + hoff[2], ca_qwT + 1 * 65536, qhB, ca_qb + 1 * HIDF, nullptr, nullptr, N2, HIDF, M_SPLITQ, ATT_SCALE * LOG2E };
            D.d[7] = { hb + hoff[0], ca_kwT + 1 * 65536, khB, ca_kb + 1 * HIDF, nullptr, nullptr, N0, HIDF, M_SPLITQ, 1.0f };
            D.d[8] = { hb + hoff[0], ca_vwT + 1 * 65536, vTB, ca_vb + 1 * HIDF, nullptr, nullptr, N0, HIDF, M_VT, 0.f };
            gemm_mfma<9><<<dim3(4, 32, 9), 256, 0, stream>>>(D, HIDF);
        }
        // flash cross-attention (both feature types in one launch; 32 rows/blk)
        {
            FlashDescArr<2> F;
            F.d[0] = { qhA, khA, vTA, caobA, N1 };
            F.d[1] = { qhB, khB, vTB, caobB, N2 };
            flash_ca<2><<<dim3(N1 / 32, NHEAD, 2), 256, 0, stream>>>(F, N0);
        }
        // CA out-projection (ADD into hg)
        {
            MGemmDescArr<2> D;
            D.d[0] = { caobA, ca_owT + 0 * 65536, hg1, ca_ob + 0 * HIDF, nullptr, nullptr, N1, HIDF, M_ADD, 0.f };
            D.d[1] = { caobB, ca_owT + 1 * 65536, hg2, ca_ob + 1 * HIDF, nullptr, nullptr, N2, HIDF, M_ADD, 0.f };
            gemm_mfma<2><<<dim3(4, 32, 2), 256, 0, stream>>>(D, HIDF);
        }

        // h = gelu(LN(h + hg)) over all types; refreshes hb
        ln_gelu_all<<<(int)NT, 256, 0, stream>>>(h0, hb, hg0, ln_g, ln_b);
    }

    // ---- output projections (bf16 MFMA, N=128) ----
    {
        MGemmDescArr<3> D;
        D.d[0] = { hb + hoff[0], outwT + 0,     dout,                            outb,       nullptr, nullptr, N0, HIDF, M_STORE, 0.f };
        D.d[1] = { hb + hoff[1], outwT + 32768, dout + (size_t)N0 * OUTF,        outb + 128, nullptr, nullptr, N1, HIDF, M_STORE, 0.f };
        D.d[2] = { hb + hoff[2], outwT + 65536, dout + (size_t)(N0 + N1) * OUTF, outb + 256, nullptr, nullptr, N2, HIDF, M_STORE, 0.f };
        gemm_mfma<3><<<dim3(2, 32, 3), 256, 0, stream>>>(D, OUTF);
    }
}

// Round 23
// 814.152 us; speedup vs baseline: 1.1076x; 1.1076x over previous
//
#include <hip/hip_runtime.h>
#include <math.h>
#include <stdint.h>
#include <stddef.h>

typedef unsigned short ushort_t;
typedef short  bf16x8 __attribute__((ext_vector_type(8)));
typedef float  f32x4  __attribute__((ext_vector_type(4)));
typedef unsigned short us4 __attribute__((ext_vector_type(4)));
typedef __bf16 bf16p2 __attribute__((ext_vector_type(2)));

// ---------------------------------------------------------------------------
static constexpr int NHEAD = 4;
static constexpr int HDIM  = 64;
static constexpr int HIDF  = 256;   // NHEAD*HDIM
static constexpr int OUTF  = 128;
static constexpr int N0 = 2048, N1 = 4096, N2 = 3072;   // participant, gene, metabolite
static constexpr int E_PG = 250000, E_GP = 250000, E_PM = 200000, E_MP = 200000;
static constexpr float ATT_SCALE = 0.125f;              // 1/sqrt(64)
static constexpr float LOG2E = 1.4426950408889634f;
static constexpr int EDGE_ITEMS = 2 * N0 + N1 + N2;     // 11264 (node,relation) items
static constexpr int E_TOT = E_GP + E_MP + E_PG + E_PM; // 900000

enum { M_STORE = 0, M_ADD = 1, M_SKIP = 2, M_B16 = 3, M_GELU_B16 = 4,
       M_SPLITQ = 5, M_VT = 6, M_STOREBOTH = 7 };

__device__ __forceinline__ float gelu_exact(float x) {
    return 0.5f * x * (1.0f + erff(x * 0.7071067811865476f));
}
__device__ __forceinline__ ushort_t f2bf(float f) {       // RNE fp32->bf16
    unsigned x = __float_as_uint(f);
    return (ushort_t)((x + 0x7fffu + ((x >> 16) & 1u)) >> 16);
}
__device__ __forceinline__ float bflo(unsigned u) { return __uint_as_float(u << 16); }
__device__ __forceinline__ float bfhi(unsigned u) { return __uint_as_float(u & 0xffff0000u); }
__device__ __forceinline__ bf16p2 asbf2(unsigned u) { return __builtin_bit_cast(bf16p2, u); }

// ---------------------------------------------------------------------------
// MFMA GEMM v2: C = epilogue(A16[M,K] @ BT16[N,K]^T + bias). Runtime mode.
// Block = 128 rows x 64 cols; each wave owns 32 rows (2 A-frags) sharing the
// 4 B-frags -> 8 MFMA per 5 loads, with 1-step register prefetch.
struct MGemmDesc { const ushort_t* A; const ushort_t* BT; void* C;
                   const float* bias; const float* skipv; void* H;
                   int M; int K; int mode; float scale; };
template <int NZ> struct MGemmDescArr { MGemmDesc d[NZ]; };

template <int NZ>
__global__ __launch_bounds__(256) void gemm_mfma(MGemmDescArr<NZ> P, int N)
{
    const MGemmDesc g = P.d[blockIdx.z];
    const int bm = blockIdx.y << 7;            // 128 rows per block
    if (bm >= g.M) return;
    const int bn = blockIdx.x << 6;
    const int tid = threadIdx.x, wave = tid >> 6, lane = tid & 63;
    const int l15 = lane & 15, lg = lane >> 4;
    const int K = g.K;
    const ushort_t* arow = g.A + (size_t)(bm + (wave << 5) + l15) * K + (lg << 3);
    const ushort_t* brow = g.BT + (size_t)(bn + l15) * K + (lg << 3);

    f32x4 acc[2][4] = {};
    bf16x8 a0 = *(const bf16x8*)(arow);
    bf16x8 a1 = *(const bf16x8*)(arow + (size_t)16 * K);
    bf16x8 bv[4];
#pragma unroll
    for (int ct = 0; ct < 4; ct++)
        bv[ct] = *(const bf16x8*)(brow + (size_t)(ct << 4) * K);

    for (int k0 = 0; k0 < K; k0 += 32) {
        const bf16x8 ca0 = a0, ca1 = a1;
        bf16x8 cb[4];
#pragma unroll
        for (int ct = 0; ct < 4; ct++) cb[ct] = bv[ct];
        if (k0 + 32 < K) {
            a0 = *(const bf16x8*)(arow + k0 + 32);
            a1 = *(const bf16x8*)(arow + (size_t)16 * K + k0 + 32);
#pragma unroll
            for (int ct = 0; ct < 4; ct++)
                bv[ct] = *(const bf16x8*)(brow + (size_t)(ct << 4) * K + k0 + 32);
        }
#pragma unroll
        for (int ct = 0; ct < 4; ct++) {
            acc[0][ct] = __builtin_amdgcn_mfma_f32_16x16x32_bf16(ca0, cb[ct], acc[0][ct], 0, 0, 0);
            acc[1][ct] = __builtin_amdgcn_mfma_f32_16x16x32_bf16(ca1, cb[ct], acc[1][ct], 0, 0, 0);
        }
    }

    const int mode = g.mode;
    float gblend = 0.f, hblend = 0.f;
    if (mode == M_SKIP) {
        const float sv = g.skipv[0];
        gblend = 1.f / (1.f + expf(-sv));
        hblend = 1.f - gblend;
    }
#pragma unroll
    for (int g2 = 0; g2 < 2; g2++) {
        const int rbase = bm + (wave << 5) + (g2 << 4);
#pragma unroll
        for (int ct = 0; ct < 4; ct++) {
            const int col = bn + (ct << 4) + l15;
            const float bia = g.bias ? g.bias[col] : 0.f;
            if (mode == M_VT) {
                const int rowb = rbase + (lg << 2);
                us4 o;
#pragma unroll
                for (int r = 0; r < 4; r++) o[r] = f2bf(acc[g2][ct][r] + bia);
                *(us4*)((ushort_t*)g.C + (size_t)col * g.M + rowb) = o;
                continue;
            }
#pragma unroll
            for (int r = 0; r < 4; r++) {
                const int row = rbase + (lg << 2) + r;
                const float v = acc[g2][ct][r] + bia;
                if (mode == M_STORE) {
                    ((float*)g.C)[(size_t)row * N + col] = v;
                } else if (mode == M_ADD) {
                    ((float*)g.C)[(size_t)row * N + col] += v;
                } else if (mode == M_SKIP) {
                    ((float*)g.C)[(size_t)row * N + col] =
                        gblend * v + hblend * ((const float*)g.H)[(size_t)row * N + col];
                } else if (mode == M_B16) {
                    ((ushort_t*)g.C)[(size_t)row * N + col] = f2bf(v);
                } else if (mode == M_GELU_B16) {
                    ((ushort_t*)g.C)[(size_t)row * N + col] = f2bf(gelu_exact(v));
                } else if (mode == M_SPLITQ) {
                    ((ushort_t*)g.C)[((size_t)(col >> 6) * g.M + row) * 64 + (col & 63)]
                        = f2bf(v * g.scale);
                } else {
                    ((float*)g.C)[(size_t)row * N + col] = v;
                    ((ushort_t*)g.H)[(size_t)row * N + col] = f2bf(v);
                }
            }
        }
    }
}

// ---------------------------------------------------------------------------
// Weight transpose+cast: W[K][N] fp32 -> WT[N][K] bf16 (desc-batched).
struct TWDesc { const float* W; ushort_t* WT; int K; int N; };
template <int ND> struct TWDescArr { TWDesc d[ND]; };

template <int ND>
__global__ __launch_bounds__(256) void transW_kernel(TWDescArr<ND> P)
{
    const TWDesc g = P.d[blockIdx.z];
    const int k0 = blockIdx.x << 6, n0 = blockIdx.y << 6;
    if (k0 >= g.K || n0 >= g.N) return;
    __shared__ float Ls[64][65];
    const int tid = threadIdx.x, c = tid & 63, rq = tid >> 6;
    for (int rr = rq; rr < 64; rr += 4)
        Ls[rr][c] = g.W[(size_t)(k0 + rr) * g.N + n0 + c];
    __syncthreads();
    for (int nn = rq; nn < 64; nn += 4)
        g.WT[(size_t)(n0 + nn) * g.K + k0 + c] = f2bf(Ls[c][nn]);
}

// fp32 -> bf16 fused cast of the three x inputs into contiguous xb
__global__ void cast3_kernel(const float* __restrict__ a, const float* __restrict__ b,
                             const float* __restrict__ c, ushort_t* __restrict__ out)
{
    constexpr int n4a = N0 * 512 / 4, n4b = N1 * 768 / 4, n4c = N2 * 384 / 4;
    int i = blockIdx.x * 256 + threadIdx.x;
    const float* src; int j;
    if (i < n4a) { src = a; j = i; }
    else if (i < n4a + n4b) { src = b; j = i - n4a; }
    else if (i < n4a + n4b + n4c) { src = c; j = i - n4a - n4b; }
    else return;
    float4 v = ((const float4*)src)[j];
    us4 o;
    o[0] = f2bf(v.x); o[1] = f2bf(v.y); o[2] = f2bf(v.z); o[3] = f2bf(v.w);
    *(us4*)(out + (size_t)i * 4) = o;
}

// ---------------------------------------------------------------------------
// Fold a_rel into qw: W'T[(h*64+d)][k] = sum_f ar[h][d][f] * qw[k][h*64+f].
struct QFDesc { const float* ar; const float* qwm; const float* qbv;
                ushort_t* wT; float* bT; };
template <int ND> struct QFDescArr { QFDesc d[ND]; };

template <int ND>
__global__ __launch_bounds__(256) void qfold_kernel(QFDescArr<ND> P)
{
    const QFDesc g = P.d[blockIdx.y];
    const int h = blockIdx.x, tid = threadIdx.x;
    __shared__ float arS[64][64];   // [d][f]
    __shared__ float qbS[64];
    for (int i = tid; i < 4096; i += 256) arS[i >> 6][i & 63] = g.ar[(h << 12) + i];
    if (tid < 64) qbS[tid] = g.qbv[(h << 6) + tid];
    __syncthreads();
    float qv[64];
    const float* qrow = g.qwm + (size_t)tid * HIDF + (h << 6);
#pragma unroll
    for (int f = 0; f < 64; f++) qv[f] = qrow[f];
#pragma unroll 4
    for (int d = 0; d < 64; d++) {
        float a = 0.f;
#pragma unroll
        for (int f = 0; f < 64; f++) a = fmaf(arS[d][f], qv[f], a);
        g.wT[(size_t)((h << 6) + d) * HIDF + tid] = f2bf(a);
    }
    if (tid < 64) {
        float b = 0.f;
#pragma unroll
        for (int f = 0; f < 64; f++) b = fmaf(arS[tid][f], qbS[f], b);
        g.bT[(h << 6) + tid] = b;
    }
}

// ---------------------------------------------------------------------------
// Expand m_rel into block-diag bf16 W^T for the agg GEMM.
struct MXDesc { const float* A; const float* B; ushort_t* out; int Kc; };
template <int ND> struct MXDescArr { MXDesc d[ND]; };

template <int ND>
__global__ void mexpand_kernel(MXDescArr<ND> P)
{
    const MXDesc g = P.d[blockIdx.y];
    const int idx = blockIdx.x * 256 + threadIdx.x;
    if (idx >= 256 * g.Kc) return;
    const int col = idx / g.Kc, k = idx - col * g.Kc;
    const int h = col >> 6, f = col & 63;
    const float* M = g.A;
    int kd = k;
    if (k >= 256) { M = g.B; kd = k - 256; }
    const int hp = kd >> 6, d = kd & 63;
    const float v = (hp == h) ? M[(h << 12) + (d << 6) + f] : 0.f;
    g.out[idx] = f2bf(v);
}

// ---------------------------------------------------------------------------
// Counting sort by destination — FUSED across the 4 relations (3 launches).
__global__ void count4_kernel(const int* __restrict__ d0, const int* __restrict__ d1,
                              const int* __restrict__ d2, const int* __restrict__ d3,
                              int* __restrict__ c0, int* __restrict__ c1,
                              int* __restrict__ c2, int* __restrict__ c3)
{
    int i = blockIdx.x * 256 + threadIdx.x;
    if (i < E_GP) { atomicAdd(&c0[d0[i]], 1); return; }
    i -= E_GP;
    if (i < E_MP) { atomicAdd(&c1[d1[i]], 1); return; }
    i -= E_MP;
    if (i < E_PG) { atomicAdd(&c2[d2[i]], 1); return; }
    i -= E_PG;
    if (i < E_PM) atomicAdd(&c3[d3[i]], 1);
}

struct ScanDesc { int* cntcur; int N; int* off; };

__global__ __launch_bounds__(256) void scan4_kernel(ScanDesc s0, ScanDesc s1,
                                                    ScanDesc s2, ScanDesc s3)
{
    const ScanDesc g = (blockIdx.x == 0) ? s0 : (blockIdx.x == 1) ? s1
                     : (blockIdx.x == 2) ? s2 : s3;
    int* cntcur = g.cntcur; const int N = g.N; int* off = g.off;
    __shared__ int sums[256];
    const int tid = threadIdx.x;
    const int base = tid * 16;
    int vals[16];
    int s = 0;
#pragma unroll
    for (int j = 0; j < 16; j++) {
        int idx = base + j;
        int c = (idx < N) ? cntcur[idx] : 0;
        vals[j] = s; s += c;
    }
    sums[tid] = s;
    __syncthreads();
    for (int d = 1; d < 256; d <<= 1) {
        int v = (tid >= d) ? sums[tid - d] : 0;
        __syncthreads();
        sums[tid] += v;
        __syncthreads();
    }
    int prefix = (tid > 0) ? sums[tid - 1] : 0;
#pragma unroll
    for (int j = 0; j < 16; j++) {
        int idx = base + j;
        if (idx < N) { int v = prefix + vals[j]; off[idx] = v; cntcur[idx] = v; }
    }
    if (tid == 255) off[N] = sums[255];
}

__global__ void scatter4_kernel(
    const int* __restrict__ s0, const int* __restrict__ d0, int* __restrict__ u0, int* __restrict__ e0,
    const int* __restrict__ s1, const int* __restrict__ d1, int* __restrict__ u1, int* __restrict__ e1,
    const int* __restrict__ s2, const int* __restrict__ d2, int* __restrict__ u2, int* __restrict__ e2,
    const int* __restrict__ s3, const int* __restrict__ d3, int* __restrict__ u3, int* __restrict__ e3)
{
    int i = blockIdx.x * 256 + threadIdx.x;
    if (i < E_GP) { e0[atomicAdd(&u0[d0[i]], 1)] = s0[i]; return; }
    i -= E_GP;
    if (i < E_MP) { e1[atomicAdd(&u1[d1[i]], 1)] = s1[i]; return; }
    i -= E_MP;
    if (i < E_PG) { e2[atomicAdd(&u2[d2[i]], 1)] = s2[i]; return; }
    i -= E_PG;
    if (i < E_PM) e3[atomicAdd(&u3[d3[i]], 1)] = s3[i];
}

// ---------------------------------------------------------------------------
// HGT edge attention core v9 — v6 structure (gathers, prefetch shadow,
// unconditional online softmax) with phase-1 dot on v_dot2_f32_bf16:
// 8 packed-dot ops replace 16 fma + 16 unpack per 16-dim slice.
__device__ __forceinline__ void edge_seg_v9(
    const bf16p2* __restrict__ qd,        // this lane's 16 Q' dims as 8 bf16 pairs
    float* __restrict__ sS,               // wave's 64-entry score LDS
    float2* __restrict__ wssh,            // wave's 64-entry {w,src} LDS
    const int* __restrict__ es, int i0, int i1,
    const ushort_t* __restrict__ Kt, const ushort_t* __restrict__ Vt,
    float pscale, int lane, int koff,
    float& m, float& plsum, float2& acc)
{
    if (i0 >= i1) return;
    const int seg = lane & 3, eidx = lane >> 2;
    const int epar = lane >> 5;
    const int dpair = (lane & 31) << 1;
    const int kbase_off = koff + (seg << 3);   // ushort offset of this lane's slice

    bool valid = (i0 + lane) < i1;
    int sidx = valid ? es[i0 + lane] : 0;
    uint4 kv[8];
#pragma unroll
    for (int p = 0; p < 4; p++) {
        const int sp = __shfl(sidx, (p << 4) + eidx);
        const ushort_t* kr = Kt + ((size_t)sp << 8) + kbase_off;
        kv[2 * p]     = *(const uint4*)(kr);
        kv[2 * p + 1] = *(const uint4*)(kr + 32);
    }

    for (int c = i0; c < i1; c += 64) {
        const int e2 = c + 64 + lane;
        const bool valid2 = e2 < i1;
        const int sidx2 = valid2 ? es[e2] : 0;

        // ---- phase 1: 16-dim partial dots via v_dot2_f32_bf16 ----
#pragma unroll
        for (int p = 0; p < 4; p++) {
            const uint4 k0 = kv[2 * p], k1 = kv[2 * p + 1];
            float dp = 0.f;
            dp = __builtin_amdgcn_fdot2_f32_bf16(asbf2(k0.x), qd[0], dp, false);
            dp = __builtin_amdgcn_fdot2_f32_bf16(asbf2(k0.y), qd[1], dp, false);
            dp = __builtin_amdgcn_fdot2_f32_bf16(asbf2(k0.z), qd[2], dp, false);
            dp = __builtin_amdgcn_fdot2_f32_bf16(asbf2(k0.w), qd[3], dp, false);
            dp = __builtin_amdgcn_fdot2_f32_bf16(asbf2(k1.x), qd[4], dp, false);
            dp = __builtin_amdgcn_fdot2_f32_bf16(asbf2(k1.y), qd[5], dp, false);
            dp = __builtin_amdgcn_fdot2_f32_bf16(asbf2(k1.z), qd[6], dp, false);
            dp = __builtin_amdgcn_fdot2_f32_bf16(asbf2(k1.w), qd[7], dp, false);
            dp += __shfl_xor(dp, 1);
            dp += __shfl_xor(dp, 2);
            if (seg == 0) sS[(p << 4) + eidx] = dp;
        }
        // ---- prefetch next chunk's K (latency hides under phases 2-3) ----
#pragma unroll
        for (int p = 0; p < 4; p++) {
            const int sp = __shfl(sidx2, (p << 4) + eidx);
            const ushort_t* kr = Kt + ((size_t)sp << 8) + kbase_off;
            kv[2 * p]     = *(const uint4*)(kr);
            kv[2 * p + 1] = *(const uint4*)(kr + 32);
        }

        const float a = valid ? sS[lane] * pscale : -INFINITY;

        // ---- phase 2: chunk max + online rescale ----
        float cm = a;
#pragma unroll
        for (int o = 32; o; o >>= 1) cm = fmaxf(cm, __shfl_xor(cm, o));
        const float mn = fmaxf(m, cm);
        const float sc = (m == -INFINITY) ? 0.f : expf(m - mn);
        const float w = valid ? expf(a - mn) : 0.f;
        plsum = plsum * sc + w;
        m = mn;
        wssh[lane] = make_float2(w, __int_as_float(sidx));

        // ---- phase 3: batched coalesced V accumulate ----
        acc.x *= sc; acc.y *= sc;
        float2 aE = make_float2(0.f, 0.f), aO = make_float2(0.f, 0.f);
#pragma unroll
        for (int b = 0; b < 64; b += 16) {
            float2 we[8];
            unsigned vv[8];
#pragma unroll
            for (int j = 0; j < 8; j++) we[j] = wssh[b + (j << 1) + epar];
#pragma unroll
            for (int j = 0; j < 8; j++) {
                const int sj = __float_as_int(we[j].y);
                vv[j] = *(const unsigned*)(Vt + (((size_t)sj) << 8) + koff + dpair);
            }
#pragma unroll
            for (int j = 0; j < 8; j++) {
                const float wj = we[j].x;
                if (j & 1) { aO.x = fmaf(wj, bflo(vv[j]), aO.x);
                             aO.y = fmaf(wj, bfhi(vv[j]), aO.y); }
                else       { aE.x = fmaf(wj, bflo(vv[j]), aE.x);
                             aE.y = fmaf(wj, bfhi(vv[j]), aE.y); }
            }
        }
        acc.x += aE.x + aO.x;
        acc.y += aE.y + aO.y;

        valid = valid2; sidx = sidx2;
    }
}

// ---------------------------------------------------------------------------
// Edge attention: ONE block per (node, relation) item — dispatch-order phase
// locality keeps each relation's K/V table hot in per-XCD L2 (grid-striding
// measured 2.6x more HBM fetch — round 14). 4 waves = 4 heads, NO barriers.
__global__ __launch_bounds__(256) void edge_attn_v9(
    const float* __restrict__ QpDA, const float* __restrict__ QpDB,
    const float* __restrict__ QpS1, const float* __restrict__ QpS2,
    const int* __restrict__ offGP, const int* __restrict__ esGP,
    const int* __restrict__ offMP, const int* __restrict__ esMP,
    const int* __restrict__ offPG, const int* __restrict__ esPG,
    const int* __restrict__ offPM, const int* __restrict__ esPM,
    const ushort_t* __restrict__ K0t, const ushort_t* __restrict__ V0t,
    const ushort_t* __restrict__ K1t, const ushort_t* __restrict__ V1t,
    const ushort_t* __restrict__ K2t, const ushort_t* __restrict__ V2t,
    const float* __restrict__ prel,
    float* __restrict__ accD, float* __restrict__ mlD,
    ushort_t* __restrict__ out1, ushort_t* __restrict__ out2)
{
    __shared__ float sS[NHEAD][64];
    __shared__ float2 wssh[NHEAD][64];
    const int b = blockIdx.x, tid = threadIdx.x, lane = tid & 63, h = tid >> 6;
    const int koff = h << 6, seg = lane & 3;

    const float* Qp; const int* off; const int* es;
    const ushort_t* Kt; const ushort_t* Vt;
    int node, r, dual = -1;
    if (b < N0)            { node = b;            Qp = QpDA; off = offGP; es = esGP; Kt = K1t; Vt = V1t; r = 1; dual = 0; }
    else if (b < 2 * N0)   { node = b - N0;       Qp = QpDB; off = offMP; es = esMP; Kt = K2t; Vt = V2t; r = 3; dual = 1; }
    else if (b < 2 * N0 + N1) { node = b - 2 * N0;      Qp = QpS1; off = offPG; es = esPG; Kt = K0t; Vt = V0t; r = 0; }
    else                      { node = b - 2 * N0 - N1; Qp = QpS2; off = offPM; es = esPM; Kt = K0t; Vt = V0t; r = 2; }

    const float* qrow = Qp + (size_t)node * HIDF + koff;
    float4 qv[4];
    qv[0] = *(const float4*)(qrow + (seg << 3));
    qv[1] = *(const float4*)(qrow + (seg << 3) + 4);
    qv[2] = *(const float4*)(qrow + 32 + (seg << 3));
    qv[3] = *(const float4*)(qrow + 32 + (seg << 3) + 4);
    bf16p2 qd[8];
#pragma unroll
    for (int i = 0; i < 4; i++) {
        const unsigned p0 = (unsigned)f2bf(qv[i].x) | ((unsigned)f2bf(qv[i].y) << 16);
        const unsigned p1 = (unsigned)f2bf(qv[i].z) | ((unsigned)f2bf(qv[i].w) << 16);
        qd[2 * i]     = asbf2(p0);
        qd[2 * i + 1] = asbf2(p1);
    }
    const float ps = prel[(r << 2) + h] * ATT_SCALE;
    float m = -INFINITY, plsum = 0.f;
    float2 acc = make_float2(0.f, 0.f);
    edge_seg_v9(qd, sS[h], wssh[h], es, off[node], off[node + 1],
                Kt, Vt, ps, lane, koff, m, plsum, acc);
    acc.x += __shfl_xor(acc.x, 32);
    acc.y += __shfl_xor(acc.y, 32);
    float l = plsum;
#pragma unroll
    for (int o = 32; o; o >>= 1) l += __shfl_xor(l, o);

    if (dual >= 0) {
        if (lane < 32)
            *(float2*)(accD + ((size_t)(dual * N0 + node)) * HIDF + koff + ((lane & 31) << 1))
                = acc;
        if (lane == 0) {
            mlD[((size_t)(dual * N0 + node)) * 8 + h * 2 + 0] = m;
            mlD[((size_t)(dual * N0 + node)) * 8 + h * 2 + 1] = l;
        }
    } else {
        const float inv = (l > 0.f) ? 1.f / l : 0.f;
        ushort_t* out = (r == 0) ? out1 : out2;
        if (lane < 32) {
            const unsigned pk = (unsigned)f2bf(acc.x * inv) | ((unsigned)f2bf(acc.y * inv) << 16);
            *(unsigned*)(out + (size_t)node * HIDF + koff + ((lane & 31) << 1)) = pk;
        }
    }
}

// Exact flash-combine of the two participant relations -> bf16 [N0][512].
__global__ __launch_bounds__(256) void combine0_kernel(
    const float* __restrict__ accD, const float* __restrict__ mlD,
    ushort_t* __restrict__ out0)
{
    const int node = blockIdx.x, col = threadIdx.x;   // col in [0,256)
    const int h = col >> 6;
    const float m0 = mlD[((size_t)node) * 8 + h * 2 + 0];
    const float l0 = mlD[((size_t)node) * 8 + h * 2 + 1];
    const float m1 = mlD[((size_t)(N0 + node)) * 8 + h * 2 + 0];
    const float l1 = mlD[((size_t)(N0 + node)) * 8 + h * 2 + 1];
    const float M = fmaxf(m0, m1);
    const float s0 = (m0 == -INFINITY) ? 0.f : expf(m0 - M);
    const float s1 = (m1 == -INFINITY) ? 0.f : expf(m1 - M);
    const float L = l0 * s0 + l1 * s1;
    const float f0 = (L > 0.f) ? s0 / L : 0.f;
    const float f1 = (L > 0.f) ? s1 / L : 0.f;
    const float a0 = accD[((size_t)node) * HIDF + col];
    const float a1 = accD[((size_t)(N0 + node)) * HIDF + col];
    out0[(size_t)node * 512 + col]       = f2bf(a0 * f0);
    out0[(size_t)node * 512 + 256 + col] = f2bf(a1 * f1);
}

// ---------------------------------------------------------------------------
// Flash cross-attention v3: 32 q-rows per block (two A fragments per wave,
// K/V registers reused across both -> 2x arithmetic intensity per K byte).
struct FlashDesc { const ushort_t* qh; const ushort_t* kh; const ushort_t* vT;
                   ushort_t* O; int Nq; };
template <int NF> struct FlashDescArr { FlashDesc d[NF]; };

template <int NF>
__global__ __launch_bounds__(256) void flash_ca(FlashDescArr<NF> P, int Nk)
{
    const FlashDesc g = P.d[blockIdx.z];
    const int q0 = blockIdx.x << 5;            // 32 q-rows per block
    if (q0 >= g.Nq) return;
    __shared__ float mS[4][32], lS[4][32];
    __shared__ __align__(16) char uS[18432];   // union: Pl[4][32][72] / oS[4][16][64]
    ushort_t (*Pl)[32][72] = (ushort_t (*)[32][72])uS;
    float    (*oS)[16][64] = (float (*)[16][64])uS;
    const int head = blockIdx.y;
    const int tid = threadIdx.x, wave = tid >> 6, lane = tid & 63;
    const int l15 = lane & 15, lg = lane >> 4;
    const int Nq = g.Nq;

    bf16x8 qa[2][2];
    {
        const ushort_t* qb0 = g.qh + ((size_t)head * Nq + q0 + l15) * 64 + (lg << 3);
        qa[0][0] = *(const bf16x8*)qb0;
        qa[0][1] = *(const bf16x8*)(qb0 + 32);
        qa[1][0] = *(const bf16x8*)(qb0 + 16 * 64);
        qa[1][1] = *(const bf16x8*)(qb0 + 16 * 64 + 32);
    }
    const ushort_t* kbase = g.kh + (size_t)head * Nk * 64;
    const ushort_t* vbase = g.vT + (size_t)head * 64 * Nk;
    const int kchunk = Nk >> 2;
    const int kbeg = wave * kchunk, kend = kbeg + kchunk;

    f32x4 o[2][4] = {};
    float m[2][4]     = {{-INFINITY,-INFINITY,-INFINITY,-INFINITY},
                         {-INFINITY,-INFINITY,-INFINITY,-INFINITY}};
    float plsum[2][4] = {};

    bf16x8 ka[8];
    {
        const ushort_t* krow = kbase + ((size_t)(kbeg + l15)) * 64 + (lg << 3);
#pragma unroll
        for (int ct = 0; ct < 4; ct++) {
            ka[ct]     = *(const bf16x8*)(krow + (ct << 10));
            ka[4 + ct] = *(const bf16x8*)(krow + (ct << 10) + 32);
        }
    }

    for (int k0 = kbeg; k0 < kend; k0 += 64) {
        bf16x8 vv[8];
        const ushort_t* vrow = vbase + (size_t)l15 * Nk + k0 + (lg << 3);
#pragma unroll
        for (int vt = 0; vt < 4; vt++) {
            vv[vt]     = *(const bf16x8*)(vrow + (size_t)(vt << 4) * Nk);
            vv[4 + vt] = *(const bf16x8*)(vrow + (size_t)(vt << 4) * Nk + 32);
        }
        f32x4 s[2][4] = {};
#pragma unroll
        for (int g2 = 0; g2 < 2; g2++)
#pragma unroll
            for (int ct = 0; ct < 4; ct++)
                s[g2][ct] = __builtin_amdgcn_mfma_f32_16x16x32_bf16(qa[g2][0], ka[ct], s[g2][ct], 0, 0, 0);
#pragma unroll
        for (int g2 = 0; g2 < 2; g2++)
#pragma unroll
            for (int ct = 0; ct < 4; ct++)
                s[g2][ct] = __builtin_amdgcn_mfma_f32_16x16x32_bf16(qa[g2][1], ka[4 + ct], s[g2][ct], 0, 0, 0);
        if (k0 + 64 < kend) {
            const ushort_t* krow2 = kbase + ((size_t)(k0 + 64 + l15)) * 64 + (lg << 3);
#pragma unroll
            for (int ct = 0; ct < 4; ct++) {
                ka[ct]     = *(const bf16x8*)(krow2 + (ct << 10));
                ka[4 + ct] = *(const bf16x8*)(krow2 + (ct << 10) + 32);
            }
        }
        float tm[2][4];
        bool need = false;
#pragma unroll
        for (int g2 = 0; g2 < 2; g2++)
#pragma unroll
            for (int r = 0; r < 4; r++) {
                tm[g2][r] = fmaxf(fmaxf(s[g2][0][r], s[g2][1][r]),
                                  fmaxf(s[g2][2][r], s[g2][3][r]));
                need = need || (tm[g2][r] > m[g2][r] + 11.54f);
            }
        if (__any(need)) {
#pragma unroll
            for (int off = 1; off <= 8; off <<= 1)
#pragma unroll
                for (int g2 = 0; g2 < 2; g2++)
#pragma unroll
                    for (int r = 0; r < 4; r++)
                        tm[g2][r] = fmaxf(tm[g2][r], __shfl_xor(tm[g2][r], off));
#pragma unroll
            for (int g2 = 0; g2 < 2; g2++)
#pragma unroll
                for (int r = 0; r < 4; r++) {
                    const float mn = fmaxf(m[g2][r], tm[g2][r]);
                    const float sc = exp2f(m[g2][r] - mn);
                    m[g2][r] = mn;
                    plsum[g2][r] *= sc;
#pragma unroll
                    for (int vt = 0; vt < 4; vt++) o[g2][vt][r] *= sc;
                }
        }
#pragma unroll
        for (int g2 = 0; g2 < 2; g2++)
#pragma unroll
            for (int ct = 0; ct < 4; ct++)
#pragma unroll
                for (int r = 0; r < 4; r++) {
                    const float p = exp2f(s[g2][ct][r] - m[g2][r]);
                    plsum[g2][r] += p;
                    Pl[wave][(g2 << 4) + (lg << 2) + r][(ct << 4) + l15] = f2bf(p);
                }
        const bf16x8 pa00 = *(const bf16x8*)&Pl[wave][l15][lg << 3];
        const bf16x8 pa01 = *(const bf16x8*)&Pl[wave][l15][32 + (lg << 3)];
        const bf16x8 pa10 = *(const bf16x8*)&Pl[wave][16 + l15][lg << 3];
        const bf16x8 pa11 = *(const bf16x8*)&Pl[wave][16 + l15][32 + (lg << 3)];
#pragma unroll
        for (int vt = 0; vt < 4; vt++) {
            o[0][vt] = __builtin_amdgcn_mfma_f32_16x16x32_bf16(pa00, vv[vt], o[0][vt], 0, 0, 0);
            o[1][vt] = __builtin_amdgcn_mfma_f32_16x16x32_bf16(pa10, vv[vt], o[1][vt], 0, 0, 0);
        }
#pragma unroll
        for (int vt = 0; vt < 4; vt++) {
            o[0][vt] = __builtin_amdgcn_mfma_f32_16x16x32_bf16(pa01, vv[4 + vt], o[0][vt], 0, 0, 0);
            o[1][vt] = __builtin_amdgcn_mfma_f32_16x16x32_bf16(pa11, vv[4 + vt], o[1][vt], 0, 0, 0);
        }
    }
#pragma unroll
    for (int off = 1; off <= 8; off <<= 1)
#pragma unroll
        for (int g2 = 0; g2 < 2; g2++)
#pragma unroll
            for (int r = 0; r < 4; r++)
                plsum[g2][r] += __shfl_xor(plsum[g2][r], off);
    if (l15 == 0) {
#pragma unroll
        for (int g2 = 0; g2 < 2; g2++)
#pragma unroll
            for (int r = 0; r < 4; r++) {
                mS[wave][(g2 << 4) + (lg << 2) + r] = m[g2][r];
                lS[wave][(g2 << 4) + (lg << 2) + r] = plsum[g2][r];
            }
    }
    __syncthreads();
#pragma unroll
    for (int g2 = 0; g2 < 2; g2++) {
        float fac[4];
#pragma unroll
        for (int r = 0; r < 4; r++) {
            const int grow = (g2 << 4) + (lg << 2) + r;
            const float ms = fmaxf(fmaxf(mS[0][grow], mS[1][grow]),
                                   fmaxf(mS[2][grow], mS[3][grow]));
            fac[r] = exp2f(m[g2][r] - ms);
        }
        __syncthreads();
#pragma unroll
        for (int vt = 0; vt < 4; vt++)
#pragma unroll
            for (int r = 0; r < 4; r++)
                oS[wave][(lg << 2) + r][(vt << 4) + l15] = o[g2][vt][r] * fac[r];
        __syncthreads();
        for (int i = tid; i < 1024; i += 256) {
            const int row = i >> 6, d = i & 63;
            const int grow = (g2 << 4) + row;
            const float m0 = mS[0][grow], m1 = mS[1][grow], m2 = mS[2][grow], m3 = mS[3][grow];
            const float ms = fmaxf(fmaxf(m0, m1), fmaxf(m2, m3));
            const float L = lS[0][grow] * exp2f(m0 - ms) + lS[1][grow] * exp2f(m1 - ms)
                          + lS[2][grow] * exp2f(m2 - ms) + lS[3][grow] * exp2f(m3 - ms);
            const float val = oS[0][row][d] + oS[1][row][d] + oS[2][row][d] + oS[3][row][d];
            g.O[(size_t)(q0 + grow) * HIDF + (head << 6) + d] = f2bf(val / L);
        }
    }
}

// ---------------------------------------------------------------------------
// Fused residual + LayerNorm + exact GELU over ALL node types in one launch.
__global__ __launch_bounds__(256) void ln_gelu_all(
    float* __restrict__ h, ushort_t* __restrict__ hb16, const float* __restrict__ hg,
    const float* __restrict__ lng, const float* __restrict__ lnb)
{
    __shared__ float t4[4];
    const int row = blockIdx.x, tid = threadIdx.x, lane = tid & 63, w = tid >> 6;
    const int t = (row >= N0) + (row >= N0 + N1);
    const size_t idx = (size_t)row * HIDF + tid;
    const float x = h[idx] + hg[idx];
    float v = x;
#pragma unroll
    for (int o = 32; o; o >>= 1) v += __shfl_xor(v, o);
    if (lane == 0) t4[w] = v;
    __syncthreads();
    const float mean = (t4[0] + t4[1] + t4[2] + t4[3]) * (1.f / 256.f);
    __syncthreads();
    const float d = x - mean;
    v = d * d;
#pragma unroll
    for (int o = 32; o; o >>= 1) v += __shfl_xor(v, o);
    if (lane == 0) t4[w] = v;
    __syncthreads();
    const float var = (t4[0] + t4[1] + t4[2] + t4[3]) * (1.f / 256.f);
    const float y = gelu_exact(d * rsqrtf(var + 1e-5f) * lng[t * HIDF + tid] + lnb[t * HIDF + tid]);
    h[idx] = y;
    hb16[idx] = f2bf(y);
}

// ---------------------------------------------------------------------------
extern "C" void kernel_launch(void* const* d_in, const int* in_sizes, int n_in,
                              void* d_out, int out_size, void* d_ws, size_t ws_size,
                              hipStream_t stream)
{
    (void)in_sizes; (void)n_in; (void)out_size; (void)ws_size;
    const float* x_p   = (const float*)d_in[0];
    const float* x_g   = (const float*)d_in[1];
    const float* x_m   = (const float*)d_in[2];
    const int*  src_pg = (const int*)d_in[3];
    const int*  dst_pg = (const int*)d_in[4];
    const int*  src_gp = (const int*)d_in[5];
    const int*  dst_gp = (const int*)d_in[6];
    const int*  src_pm = (const int*)d_in[7];
    const int*  dst_pm = (const int*)d_in[8];
    const int*  src_mp = (const int*)d_in[9];
    const int*  dst_mp = (const int*)d_in[10];
    const float* Win_p = (const float*)d_in[11];
    const float* bin_p = (const float*)d_in[12];
    const float* Win_g = (const float*)d_in[13];
    const float* bin_g = (const float*)d_in[14];
    const float* Win_m = (const float*)d_in[15];
    const float* bin_m = (const float*)d_in[16];
    const float* kw    = (const float*)d_in[17];
    const float* qw    = (const float*)d_in[18];
    const float* vw    = (const float*)d_in[19];
    const float* aw    = (const float*)d_in[20];
    const float* kb    = (const float*)d_in[21];
    const float* qb    = (const float*)d_in[22];
    const float* vb    = (const float*)d_in[23];
    const float* ab    = (const float*)d_in[24];
    const float* skip  = (const float*)d_in[25];
    const float* a_rel = (const float*)d_in[26];
    const float* m_rel = (const float*)d_in[27];
    const float* p_rel = (const float*)d_in[28];
    const float* ca_qw = (const float*)d_in[29];
    const float* ca_kw = (const float*)d_in[30];
    const float* ca_vw = (const float*)d_in[31];
    const float* ca_ow = (const float*)d_in[32];
    const float* ca_qb = (const float*)d_in[33];
    const float* ca_kb = (const float*)d_in[34];
    const float* ca_vb = (const float*)d_in[35];
    const float* ca_ob = (const float*)d_in[36];
    const float* ln_g  = (const float*)d_in[37];
    const float* ln_b  = (const float*)d_in[38];
    const float* outw  = (const float*)d_in[39];
    const float* outb  = (const float*)d_in[40];
    float* dout = (float*)d_out;

    // ---- workspace carve-up ----
    float* Wp = (float*)d_ws;
    size_t cursz = 0;
    auto alloc = [&](size_t n) -> float* {
        float* p = Wp + cursz; cursz += (n + 63) & ~(size_t)63; return p;
    };
    const size_t NT = N0 + N1 + N2;               // 9216
    float* h0  = alloc((size_t)N0 * HIDF);
    float* h1  = alloc((size_t)N1 * HIDF);
    float* h2  = alloc((size_t)N2 * HIDF);
    float* hg0 = alloc((size_t)N0 * HIDF);
    float* hg1 = alloc((size_t)N1 * HIDF);
    float* hg2 = alloc((size_t)N2 * HIDF);
    ushort_t* hb  = (ushort_t*)alloc(NT * HIDF / 2);
    ushort_t* K16 = (ushort_t*)alloc(NT * HIDF / 2);
    ushort_t* V16 = (ushort_t*)alloc(NT * HIDF / 2);
    ushort_t* K16_0 = K16, *K16_1 = K16 + (size_t)N0 * HIDF, *K16_2 = K16 + (size_t)(N0 + N1) * HIDF;
    ushort_t* V16_0 = V16, *V16_1 = V16 + (size_t)N0 * HIDF, *V16_2 = V16 + (size_t)(N0 + N1) * HIDF;
    float* QpPool  = alloc((size_t)(N1 + N0 + N2 + N0) * HIDF);   // fp32 Q' x4
    float* Qp0 = QpPool;
    float* Qp1 = Qp0 + (size_t)N1 * HIDF;
    float* Qp2 = Qp1 + (size_t)N0 * HIDF;
    float* Qp3 = Qp2 + (size_t)N2 * HIDF;
    float* accD = alloc((size_t)2 * N0 * HIDF);                   // dual fp32 partials
    float* mlD  = alloc((size_t)2 * N0 * 8);                      // dual (m,l) per head
    ushort_t* part0b = (ushort_t*)alloc((size_t)N0 * 512 / 2);    // [N0][512] bf16
    ushort_t* part1b = (ushort_t*)alloc((size_t)N1 * HIDF / 2);
    ushort_t* part2b = (ushort_t*)alloc((size_t)N2 * HIDF / 2);
    ushort_t* aggb16 = (ushort_t*)alloc(NT * HIDF / 2);
    ushort_t* qhA   = (ushort_t*)alloc((size_t)N1 * HIDF / 2);
    ushort_t* qhB   = (ushort_t*)alloc((size_t)N2 * HIDF / 2);
    ushort_t* khA   = (ushort_t*)alloc((size_t)N0 * HIDF / 2);
    ushort_t* khB   = (ushort_t*)alloc((size_t)N0 * HIDF / 2);
    ushort_t* vTA   = (ushort_t*)alloc((size_t)N0 * HIDF / 2);
    ushort_t* vTB   = (ushort_t*)alloc((size_t)N0 * HIDF / 2);
    ushort_t* caobA = (ushort_t*)alloc((size_t)N1 * HIDF / 2);
    ushort_t* caobB = (ushort_t*)alloc((size_t)N2 * HIDF / 2);
    ushort_t* WT16 = (ushort_t*)alloc(2621440 / 2);               // transposed weights
    ushort_t* WqpT = (ushort_t*)alloc((size_t)8 * 65536 / 2);     // folded Q' weights
    float*    bqp  = alloc(8 * 256);                              // folded Q' biases
    ushort_t* WmT  = (ushort_t*)alloc((size_t)2 * 262144 / 2);    // expanded m_rel
    // bf16 x inputs alias QpPool (dead before layer loop)
    ushort_t* xb = (ushort_t*)QpPool;
    int* es_gp = (int*)alloc(E_GP);
    int* es_mp = (int*)alloc(E_MP);
    int* es_pg = (int*)alloc(E_PG);
    int* es_pm = (int*)alloc(E_PM);
    int* off_gp = (int*)alloc(N0 + 1);
    int* off_mp = (int*)alloc(N0 + 1);
    int* off_pg = (int*)alloc(N1 + 1);
    int* off_pm = (int*)alloc(N2 + 1);
    // contiguous cur arrays -> single memset
    int* cur_all = (int*)alloc(2 * N0 + N1 + N2);
    int* cur_gp = cur_all;
    int* cur_mp = cur_all + N0;
    int* cur_pg = cur_all + 2 * N0;
    int* cur_pm = cur_all + 2 * N0 + N1;

    // WT16 sub-offsets (ushort units)
    ushort_t* kwT    = WT16;
    ushort_t* vwT    = WT16 + 6 * 65536;
    ushort_t* awT    = WT16 + 12 * 65536;
    ushort_t* ca_qwT = WT16 + 18 * 65536;
    ushort_t* ca_kwT = WT16 + 20 * 65536;
    ushort_t* ca_vwT = WT16 + 22 * 65536;
    ushort_t* ca_owT = WT16 + 24 * 65536;
    ushort_t* outwT  = WT16 + 26 * 65536;
    ushort_t* WinTp  = outwT + 3 * 32768;
    ushort_t* WinTg  = WinTp + 256 * 512;
    ushort_t* WinTm  = WinTg + 256 * 768;

    // ---- weight transpose+cast (32 matrices; qw folded separately) ----
    {
        TWDescArr<32> T;
        for (int i = 0; i < 6; i++) {
            T.d[i]      = { kw + (size_t)i * 65536, kwT + (size_t)i * 65536, 256, 256 };
            T.d[6 + i]  = { vw + (size_t)i * 65536, vwT + (size_t)i * 65536, 256, 256 };
            T.d[12 + i] = { aw + (size_t)i * 65536, awT + (size_t)i * 65536, 256, 256 };
        }
        for (int c = 0; c < 2; c++) {
            T.d[18 + c] = { ca_qw + (size_t)c * 65536, ca_qwT + (size_t)c * 65536, 256, 256 };
            T.d[20 + c] = { ca_kw + (size_t)c * 65536, ca_kwT + (size_t)c * 65536, 256, 256 };
            T.d[22 + c] = { ca_vw + (size_t)c * 65536, ca_vwT + (size_t)c * 65536, 256, 256 };
            T.d[24 + c] = { ca_ow + (size_t)c * 65536, ca_owT + (size_t)c * 65536, 256, 256 };
        }
        for (int t = 0; t < 3; t++)
            T.d[26 + t] = { outw + (size_t)t * 32768, outwT + (size_t)t * 32768, 256, 128 };
        T.d[29] = { Win_p, WinTp, 512, 256 };
        T.d[30] = { Win_g, WinTg, 768, 256 };
        T.d[31] = { Win_m, WinTm, 384, 256 };
        transW_kernel<32><<<dim3(12, 4, 32), 256, 0, stream>>>(T);
    }
    // ---- fold a_rel into qw (8 = L x 4 relations); dst(r) = {1,0,2,0} ----
    {
        const int dstt[4] = { 1, 0, 2, 0 };
        QFDescArr<8> Q;
        for (int l = 0; l < 2; l++)
            for (int r = 0; r < 4; r++) {
                const int z = l * 4 + r, dt = dstt[r];
                Q.d[z] = { a_rel + (size_t)z * 16384,
                           qw + (size_t)(l * 3 + dt) * 65536,
                           qb + (size_t)(l * 3 + dt) * 256,
                           WqpT + (size_t)z * 65536, bqp + (size_t)z * 256 };
            }
        qfold_kernel<8><<<dim3(NHEAD, 8), 256, 0, stream>>>(Q);
    }
    // ---- expand m_rel block-diag (per layer: dual K=512, singles K=256) ----
    ushort_t* WmT_l[2][3];
    {
        MXDescArr<6> X;
        for (int l = 0; l < 2; l++) {
            ushort_t* base = WmT + (size_t)l * 262144;
            WmT_l[l][0] = base;
            WmT_l[l][1] = base + 131072;
            WmT_l[l][2] = base + 196608;
            const float* mr = m_rel + (size_t)l * 4 * 16384;
            X.d[l * 3 + 0] = { mr + 1 * 16384, mr + 3 * 16384, WmT_l[l][0], 512 };
            X.d[l * 3 + 1] = { mr + 0 * 16384, nullptr,        WmT_l[l][1], 256 };
            X.d[l * 3 + 2] = { mr + 2 * 16384, nullptr,        WmT_l[l][2], 256 };
        }
        mexpand_kernel<6><<<dim3(512, 6), 256, 0, stream>>>(X);
    }

    // ---- counting-sort edges by destination — FUSED (4 launches total) ----
    hipMemsetAsync(cur_all, 0, (2 * N0 + N1 + N2) * sizeof(int), stream);
    count4_kernel<<<(E_TOT + 255) / 256, 256, 0, stream>>>(
        dst_gp, dst_mp, dst_pg, dst_pm, cur_gp, cur_mp, cur_pg, cur_pm);
    {
        ScanDesc s0 = { cur_gp, N0, off_gp };
        ScanDesc s1 = { cur_mp, N0, off_mp };
        ScanDesc s2 = { cur_pg, N1, off_pg };
        ScanDesc s3 = { cur_pm, N2, off_pm };
        scan4_kernel<<<4, 256, 0, stream>>>(s0, s1, s2, s3);
    }
    scatter4_kernel<<<(E_TOT + 255) / 256, 256, 0, stream>>>(
        src_gp, dst_gp, cur_gp, es_gp,
        src_mp, dst_mp, cur_mp, es_mp,
        src_pg, dst_pg, cur_pg, es_pg,
        src_pm, dst_pm, cur_pm, es_pm);

    float* hgptr[3] = { hg0, hg1, hg2 };
    float* hptr[3]  = { h0, h1, h2 };
    const int Ns[3] = { N0, N1, N2 };
    const size_t hoff[3] = { 0, (size_t)N0 * HIDF, (size_t)(N0 + N1) * HIDF };

    // ---- input projections (STOREBOTH: h fp32 + hb bf16) ----
    {
        constexpr int n4tot = (N0 * 512 + N1 * 768 + N2 * 384) / 4;
        cast3_kernel<<<(n4tot + 255) / 256, 256, 0, stream>>>(x_p, x_g, x_m, xb);
    }
    const size_t xoff1 = (size_t)N0 * 512, xoff2 = xoff1 + (size_t)N1 * 768;
    {
        MGemmDescArr<3> D;
        D.d[0] = { xb,         WinTp, h0, bin_p, nullptr, hb + hoff[0], N0, 512, M_STOREBOTH, 0.f };
        D.d[1] = { xb + xoff1, WinTg, h1, bin_g, nullptr, hb + hoff[1], N1, 768, M_STOREBOTH, 0.f };
        D.d[2] = { xb + xoff2, WinTm, h2, bin_m, nullptr, hb + hoff[2], N2, 384, M_STOREBOTH, 0.f };
        gemm_mfma<3><<<dim3(4, 32, 3), 256, 0, stream>>>(D, HIDF);
    }

    for (int l = 0; l < 2; l++) {
        // Q' (folded a_rel, x4) + K/V projections (x6) in ONE launch
        {
            ushort_t* Kp[3] = { K16_0, K16_1, K16_2 };
            ushort_t* Vp[3] = { V16_0, V16_1, V16_2 };
            const size_t zb = (size_t)l * 4;
            MGemmDescArr<10> D;
            D.d[0] = { hb + hoff[1], WqpT + (zb + 0) * 65536, Qp0, bqp + (zb + 0) * 256, nullptr, nullptr, N1, HIDF, M_STORE, 0.f };
            D.d[1] = { hb + hoff[0], WqpT + (zb + 1) * 65536, Qp1, bqp + (zb + 1) * 256, nullptr, nullptr, N0, HIDF, M_STORE, 0.f };
            D.d[2] = { hb + hoff[2], WqpT + (zb + 2) * 65536, Qp2, bqp + (zb + 2) * 256, nullptr, nullptr, N2, HIDF, M_STORE, 0.f };
            D.d[3] = { hb + hoff[0], WqpT + (zb + 3) * 65536, Qp3, bqp + (zb + 3) * 256, nullptr, nullptr, N0, HIDF, M_STORE, 0.f };
            for (int t = 0; t < 3; t++) {
                D.d[4 + t] = { hb + hoff[t], kwT + (size_t)(l * 3 + t) * 65536, Kp[t],
                               kb + (size_t)(l * 3 + t) * HIDF, nullptr, nullptr, Ns[t], HIDF, M_B16, 0.f };
                D.d[7 + t] = { hb + hoff[t], vwT + (size_t)(l * 3 + t) * 65536, Vp[t],
                               vb + (size_t)(l * 3 + t) * HIDF, nullptr, nullptr, Ns[t], HIDF, M_B16, 0.f };
            }
            gemm_mfma<10><<<dim3(4, 32, 10), 256, 0, stream>>>(D, HIDF);
        }
        // segment-softmax edge attention: one block per (node, relation)
        const float* prl = p_rel + (size_t)l * 16;
        edge_attn_v9<<<EDGE_ITEMS, 256, 0, stream>>>(
            Qp1, Qp3, Qp0, Qp2,
            off_gp, es_gp, off_mp, es_mp, off_pg, es_pg, off_pm, es_pm,
            K16_0, V16_0, K16_1, V16_1, K16_2, V16_2,
            prl, accD, mlD, part1b, part2b);
        combine0_kernel<<<N0, 256, 0, stream>>>(accD, mlD, part0b);
        // agg = gelu(sum_r partial_r @ m_rel[r]) -> bf16 (fused epilogue)
        {
            MGemmDescArr<3> D;
            D.d[0] = { part0b, WmT_l[l][0], aggb16 + hoff[0], nullptr, nullptr, nullptr, N0, 512, M_GELU_B16, 0.f };
            D.d[1] = { part1b, WmT_l[l][1], aggb16 + hoff[1], nullptr, nullptr, nullptr, N1, 256, M_GELU_B16, 0.f };
            D.d[2] = { part2b, WmT_l[l][2], aggb16 + hoff[2], nullptr, nullptr, nullptr, N2, 256, M_GELU_B16, 0.f };
            gemm_mfma<3><<<dim3(4, 32, 3), 256, 0, stream>>>(D, HIDF);
        }
        // hg-skip (x3) + CA projections (x6) in ONE launch (independent)
        {
            MGemmDescArr<9> D;
            for (int t = 0; t < 3; t++)
                D.d[t] = { aggb16 + hoff[t], awT + (size_t)(l * 3 + t) * 65536, hgptr[t],
                           ab + (size_t)(l * 3 + t) * HIDF, skip + l * 3 + t, hptr[t], Ns[t], HIDF, M_SKIP, 0.f };
            D.d[3] = { hb + hoff[1], ca_qwT + 0 * 65536, qhA, ca_qb + 0 * HIDF, nullptr, nullptr, N1, HIDF, M_SPLITQ, ATT_SCALE * LOG2E };
            D.d[4] = { hb + hoff[0], ca_kwT + 0 * 65536, khA, ca_kb + 0 * HIDF, nullptr, nullptr, N0, HIDF, M_SPLITQ, 1.0f };
            D.d[5] = { hb + hoff[0], ca_vwT + 0 * 65536, vTA, ca_vb + 0 * HIDF, nullptr, nullptr, N0, HIDF, M_VT, 0.f };
            D.d[6] = { hb + hoff[2], ca_qwT + 1 * 65536, qhB, ca_qb + 1 * HIDF, nullptr, nullptr, N2, HIDF, M_SPLITQ, ATT_SCALE * LOG2E };
            D.d[7] = { hb + hoff[0], ca_kwT + 1 * 65536, khB, ca_kb + 1 * HIDF, nullptr, nullptr, N0, HIDF, M_SPLITQ, 1.0f };
            D.d[8] = { hb + hoff[0], ca_vwT + 1 * 65536, vTB, ca_vb + 1 * HIDF, nullptr, nullptr, N0, HIDF, M_VT, 0.f };
            gemm_mfma<9><<<dim3(4, 32, 9), 256, 0, stream>>>(D, HIDF);
        }
        // flash cross-attention (both feature types in one launch; 32 rows/blk)
        {
            FlashDescArr<2> F;
            F.d[0] = { qhA, khA, vTA, caobA, N1 };
            F.d[1] = { qhB, khB, vTB, caobB, N2 };
            flash_ca<2><<<dim3(N1 / 32, NHEAD, 2), 256, 0, stream>>>(F, N0);
        }
        // CA out-projection (ADD into hg)
        {
            MGemmDescArr<2> D;
            D.d[0] = { caobA, ca_owT + 0 * 65536, hg1, ca_ob + 0 * HIDF, nullptr, nullptr, N1, HIDF, M_ADD, 0.f };
            D.d[1] = { caobB, ca_owT + 1 * 65536, hg2, ca_ob + 1 * HIDF, nullptr, nullptr, N2, HIDF, M_ADD, 0.f };
            gemm_mfma<2><<<dim3(4, 32, 2), 256, 0, stream>>>(D, HIDF);
        }

        // h = gelu(LN(h + hg)) over all types; refreshes hb
        ln_gelu_all<<<(int)NT, 256, 0, stream>>>(h0, hb, hg0, ln_g, ln_b);
    }

    // ---- output projections (bf16 MFMA, N=128) ----
    {
        MGemmDescArr<3> D;
        D.d[0] = { hb + hoff[0], outwT + 0,     dout,                            outb,       nullptr, nullptr, N0, HIDF, M_STORE, 0.f };
        D.d[1] = { hb + hoff[1], outwT + 32768, dout + (size_t)N0 * OUTF,        outb + 128, nullptr, nullptr, N1, HIDF, M_STORE, 0.f };
        D.d[2] = { hb + hoff[2], outwT + 65536, dout + (size_t)(N0 + N1) * OUTF, outb + 256, nullptr, nullptr, N2, HIDF, M_STORE, 0.f };
        gemm_mfma<3><<<dim3(2, 32, 3), 256, 0, stream>>>(D, OUTF);
    }
}

// Round 24
// 796.002 us; speedup vs baseline: 1.1329x; 1.0228x over previous
//
#include <hip/hip_runtime.h>
#include <math.h>
#include <stdint.h>
#include <stddef.h>

typedef unsigned short ushort_t;
typedef short  bf16x8 __attribute__((ext_vector_type(8)));
typedef float  f32x4  __attribute__((ext_vector_type(4)));
typedef unsigned short us4 __attribute__((ext_vector_type(4)));
typedef __bf16 bf16p2 __attribute__((ext_vector_type(2)));

// ---------------------------------------------------------------------------
static constexpr int NHEAD = 4;
static constexpr int HDIM  = 64;
static constexpr int HIDF  = 256;   // NHEAD*HDIM
static constexpr int OUTF  = 128;
static constexpr int N0 = 2048, N1 = 4096, N2 = 3072;   // participant, gene, metabolite
static constexpr int E_PG = 250000, E_GP = 250000, E_PM = 200000, E_MP = 200000;
static constexpr float ATT_SCALE = 0.125f;              // 1/sqrt(64)
static constexpr float LOG2E = 1.4426950408889634f;
static constexpr int EDGE_ITEMS = 2 * N0 + N1 + N2;     // 11264 (node,relation) items
static constexpr int E_TOT = E_GP + E_MP + E_PG + E_PM; // 900000

enum { M_STORE = 0, M_ADD = 1, M_SKIP = 2, M_B16 = 3, M_GELU_B16 = 4,
       M_SPLITQ = 5, M_VT = 6, M_STOREBOTH = 7 };

__device__ __forceinline__ float gelu_exact(float x) {
    return 0.5f * x * (1.0f + erff(x * 0.7071067811865476f));
}
__device__ __forceinline__ ushort_t f2bf(float f) {       // RNE fp32->bf16
    unsigned x = __float_as_uint(f);
    return (ushort_t)((x + 0x7fffu + ((x >> 16) & 1u)) >> 16);
}
__device__ __forceinline__ float bflo(unsigned u) { return __uint_as_float(u << 16); }
__device__ __forceinline__ float bfhi(unsigned u) { return __uint_as_float(u & 0xffff0000u); }
__device__ __forceinline__ bf16p2 asbf2(unsigned u) { return __builtin_bit_cast(bf16p2, u); }

// ---------------------------------------------------------------------------
// MFMA GEMM v2: C = epilogue(A16[M,K] @ BT16[N,K]^T + bias). Runtime mode.
// Block = 128 rows x 64 cols; each wave owns 32 rows (2 A-frags) sharing the
// 4 B-frags -> 8 MFMA per 5 loads, with 1-step register prefetch.
struct MGemmDesc { const ushort_t* A; const ushort_t* BT; void* C;
                   const float* bias; const float* skipv; void* H;
                   int M; int K; int mode; float scale; };
template <int NZ> struct MGemmDescArr { MGemmDesc d[NZ]; };

template <int NZ>
__global__ __launch_bounds__(256) void gemm_mfma(MGemmDescArr<NZ> P, int N)
{
    const MGemmDesc g = P.d[blockIdx.z];
    const int bm = blockIdx.y << 7;            // 128 rows per block
    if (bm >= g.M) return;
    const int bn = blockIdx.x << 6;
    const int tid = threadIdx.x, wave = tid >> 6, lane = tid & 63;
    const int l15 = lane & 15, lg = lane >> 4;
    const int K = g.K;
    const ushort_t* arow = g.A + (size_t)(bm + (wave << 5) + l15) * K + (lg << 3);
    const ushort_t* brow = g.BT + (size_t)(bn + l15) * K + (lg << 3);

    f32x4 acc[2][4] = {};
    bf16x8 a0 = *(const bf16x8*)(arow);
    bf16x8 a1 = *(const bf16x8*)(arow + (size_t)16 * K);
    bf16x8 bv[4];
#pragma unroll
    for (int ct = 0; ct < 4; ct++)
        bv[ct] = *(const bf16x8*)(brow + (size_t)(ct << 4) * K);

    for (int k0 = 0; k0 < K; k0 += 32) {
        const bf16x8 ca0 = a0, ca1 = a1;
        bf16x8 cb[4];
#pragma unroll
        for (int ct = 0; ct < 4; ct++) cb[ct] = bv[ct];
        if (k0 + 32 < K) {
            a0 = *(const bf16x8*)(arow + k0 + 32);
            a1 = *(const bf16x8*)(arow + (size_t)16 * K + k0 + 32);
#pragma unroll
            for (int ct = 0; ct < 4; ct++)
                bv[ct] = *(const bf16x8*)(brow + (size_t)(ct << 4) * K + k0 + 32);
        }
#pragma unroll
        for (int ct = 0; ct < 4; ct++) {
            acc[0][ct] = __builtin_amdgcn_mfma_f32_16x16x32_bf16(ca0, cb[ct], acc[0][ct], 0, 0, 0);
            acc[1][ct] = __builtin_amdgcn_mfma_f32_16x16x32_bf16(ca1, cb[ct], acc[1][ct], 0, 0, 0);
        }
    }

    const int mode = g.mode;
    float gblend = 0.f, hblend = 0.f;
    if (mode == M_SKIP) {
        const float sv = g.skipv[0];
        gblend = 1.f / (1.f + expf(-sv));
        hblend = 1.f - gblend;
    }
#pragma unroll
    for (int g2 = 0; g2 < 2; g2++) {
        const int rbase = bm + (wave << 5) + (g2 << 4);
#pragma unroll
        for (int ct = 0; ct < 4; ct++) {
            const int col = bn + (ct << 4) + l15;
            const float bia = g.bias ? g.bias[col] : 0.f;
            if (mode == M_VT) {
                const int rowb = rbase + (lg << 2);
                us4 o;
#pragma unroll
                for (int r = 0; r < 4; r++) o[r] = f2bf(acc[g2][ct][r] + bia);
                *(us4*)((ushort_t*)g.C + (size_t)col * g.M + rowb) = o;
                continue;
            }
#pragma unroll
            for (int r = 0; r < 4; r++) {
                const int row = rbase + (lg << 2) + r;
                const float v = acc[g2][ct][r] + bia;
                if (mode == M_STORE) {
                    ((float*)g.C)[(size_t)row * N + col] = v;
                } else if (mode == M_ADD) {
                    ((float*)g.C)[(size_t)row * N + col] += v;
                } else if (mode == M_SKIP) {
                    ((float*)g.C)[(size_t)row * N + col] =
                        gblend * v + hblend * ((const float*)g.H)[(size_t)row * N + col];
                } else if (mode == M_B16) {
                    ((ushort_t*)g.C)[(size_t)row * N + col] = f2bf(v);
                } else if (mode == M_GELU_B16) {
                    ((ushort_t*)g.C)[(size_t)row * N + col] = f2bf(gelu_exact(v));
                } else if (mode == M_SPLITQ) {
                    ((ushort_t*)g.C)[((size_t)(col >> 6) * g.M + row) * 64 + (col & 63)]
                        = f2bf(v * g.scale);
                } else {
                    ((float*)g.C)[(size_t)row * N + col] = v;
                    ((ushort_t*)g.H)[(size_t)row * N + col] = f2bf(v);
                }
            }
        }
    }
}

// ---------------------------------------------------------------------------
// Preprocessing descriptors
struct TWDesc { const float* W; ushort_t* WT; int K; int N; };
template <int ND> struct TWDescArr { TWDesc d[ND]; };
struct QFDesc { const float* ar; const float* qwm; const float* qbv;
                ushort_t* wT; float* bT; };
template <int ND> struct QFDescArr { QFDesc d[ND]; };
struct MXDesc { const float* A; const float* B; ushort_t* out; int Kc; };
template <int ND> struct MXDescArr { MXDesc d[ND]; };

// Fused preprocessing: transW(32 descs) + qfold(8) + mexpand(6) + cast3 +
// cur-zeroing in ONE launch (block-index-range dispatch). Saves 4 launches.
struct PreprocArgs {
    TWDescArr<32> T;
    QFDescArr<8> Q;
    MXDescArr<6> X;
    const float* xa; const float* xg; const float* xm; ushort_t* xb;
    int* cur_all;
};
static constexpr int PB_TW = 1536;            // 12 x 4 x 32
static constexpr int PB_QF = PB_TW + 32;      // 4 x 8
static constexpr int PB_MX = PB_QF + 3072;    // 512 x 6
static constexpr int PB_C3 = PB_MX + 5248;    // cast blocks
static constexpr int PB_Z  = PB_C3 + 44;      // zero blocks

__global__ __launch_bounds__(256) void preproc_kernel(PreprocArgs P)
{
    __shared__ __align__(16) char lsbuf[16640];   // transW Ls[64][65] / qfold arS+qbS
    const int b = blockIdx.x, tid = threadIdx.x;
    if (b < PB_TW) {
        const int z = b / 48, rem = b - z * 48;
        const int kx = rem % 12, ny = rem / 12;
        const TWDesc g = P.T.d[z];
        const int k0 = kx << 6, n0 = ny << 6;
        if (k0 >= g.K || n0 >= g.N) return;
        float (*Ls)[65] = (float (*)[65])lsbuf;
        const int c = tid & 63, rq = tid >> 6;
        for (int rr = rq; rr < 64; rr += 4)
            Ls[rr][c] = g.W[(size_t)(k0 + rr) * g.N + n0 + c];
        __syncthreads();
        for (int nn = rq; nn < 64; nn += 4)
            g.WT[(size_t)(n0 + nn) * g.K + k0 + c] = f2bf(Ls[c][nn]);
        return;
    }
    if (b < PB_QF) {
        const int idx = b - PB_TW;
        const int h = idx & 3, z = idx >> 2;
        const QFDesc g = P.Q.d[z];
        float (*arS)[64] = (float (*)[64])lsbuf;
        float* qbS = (float*)(lsbuf + 64 * 64 * 4);
        for (int i = tid; i < 4096; i += 256) arS[i >> 6][i & 63] = g.ar[(h << 12) + i];
        if (tid < 64) qbS[tid] = g.qbv[(h << 6) + tid];
        __syncthreads();
        float qv[64];
        const float* qrow = g.qwm + (size_t)tid * HIDF + (h << 6);
#pragma unroll
        for (int f = 0; f < 64; f++) qv[f] = qrow[f];
#pragma unroll 4
        for (int d = 0; d < 64; d++) {
            float a = 0.f;
#pragma unroll
            for (int f = 0; f < 64; f++) a = fmaf(arS[d][f], qv[f], a);
            g.wT[(size_t)((h << 6) + d) * HIDF + tid] = f2bf(a);
        }
        if (tid < 64) {
            float bb = 0.f;
#pragma unroll
            for (int f = 0; f < 64; f++) bb = fmaf(arS[tid][f], qbS[f], bb);
            g.bT[(h << 6) + tid] = bb;
        }
        return;
    }
    if (b < PB_MX) {
        const int idx0 = b - PB_QF;
        const int x = idx0 & 511, y = idx0 >> 9;
        const MXDesc g = P.X.d[y];
        const int idx = x * 256 + tid;
        if (idx >= 256 * g.Kc) return;
        const int col = idx / g.Kc, k = idx - col * g.Kc;
        const int h = col >> 6, f = col & 63;
        const float* M = g.A;
        int kd = k;
        if (k >= 256) { M = g.B; kd = k - 256; }
        const int hp = kd >> 6, d = kd & 63;
        const float v = (hp == h) ? M[(h << 12) + (d << 6) + f] : 0.f;
        g.out[idx] = f2bf(v);
        return;
    }
    if (b < PB_C3) {
        constexpr int n4a = N0 * 512 / 4, n4b = N1 * 768 / 4, n4c = N2 * 384 / 4;
        int i = (b - PB_MX) * 256 + tid;
        const float* src; int j;
        if (i < n4a) { src = P.xa; j = i; }
        else if (i < n4a + n4b) { src = P.xg; j = i - n4a; }
        else if (i < n4a + n4b + n4c) { src = P.xm; j = i - n4a - n4b; }
        else return;
        float4 v = ((const float4*)src)[j];
        us4 o;
        o[0] = f2bf(v.x); o[1] = f2bf(v.y); o[2] = f2bf(v.z); o[3] = f2bf(v.w);
        *(us4*)(P.xb + (size_t)i * 4) = o;
        return;
    }
    {
        int i = (b - PB_C3) * 256 + tid;
        if (i < 2 * N0 + N1 + N2) P.cur_all[i] = 0;
    }
}

// ---------------------------------------------------------------------------
// Counting sort by destination — FUSED across the 4 relations.
__global__ void count4_kernel(const int* __restrict__ d0, const int* __restrict__ d1,
                              const int* __restrict__ d2, const int* __restrict__ d3,
                              int* __restrict__ c0, int* __restrict__ c1,
                              int* __restrict__ c2, int* __restrict__ c3)
{
    int i = blockIdx.x * 256 + threadIdx.x;
    if (i < E_GP) { atomicAdd(&c0[d0[i]], 1); return; }
    i -= E_GP;
    if (i < E_MP) { atomicAdd(&c1[d1[i]], 1); return; }
    i -= E_MP;
    if (i < E_PG) { atomicAdd(&c2[d2[i]], 1); return; }
    i -= E_PG;
    if (i < E_PM) atomicAdd(&c3[d3[i]], 1);
}

struct ScanDesc { int* cntcur; int N; int* off; };

__global__ __launch_bounds__(256) void scan4_kernel(ScanDesc s0, ScanDesc s1,
                                                    ScanDesc s2, ScanDesc s3)
{
    const ScanDesc g = (blockIdx.x == 0) ? s0 : (blockIdx.x == 1) ? s1
                     : (blockIdx.x == 2) ? s2 : s3;
    int* cntcur = g.cntcur; const int N = g.N; int* off = g.off;
    __shared__ int sums[256];
    const int tid = threadIdx.x;
    const int base = tid * 16;
    int vals[16];
    int s = 0;
#pragma unroll
    for (int j = 0; j < 16; j++) {
        int idx = base + j;
        int c = (idx < N) ? cntcur[idx] : 0;
        vals[j] = s; s += c;
    }
    sums[tid] = s;
    __syncthreads();
    for (int d = 1; d < 256; d <<= 1) {
        int v = (tid >= d) ? sums[tid - d] : 0;
        __syncthreads();
        sums[tid] += v;
        __syncthreads();
    }
    int prefix = (tid > 0) ? sums[tid - 1] : 0;
#pragma unroll
    for (int j = 0; j < 16; j++) {
        int idx = base + j;
        if (idx < N) { int v = prefix + vals[j]; off[idx] = v; cntcur[idx] = v; }
    }
    if (tid == 255) off[N] = sums[255];
}

__global__ void scatter4_kernel(
    const int* __restrict__ s0, const int* __restrict__ d0, int* __restrict__ u0, int* __restrict__ e0,
    const int* __restrict__ s1, const int* __restrict__ d1, int* __restrict__ u1, int* __restrict__ e1,
    const int* __restrict__ s2, const int* __restrict__ d2, int* __restrict__ u2, int* __restrict__ e2,
    const int* __restrict__ s3, const int* __restrict__ d3, int* __restrict__ u3, int* __restrict__ e3)
{
    int i = blockIdx.x * 256 + threadIdx.x;
    if (i < E_GP) { e0[atomicAdd(&u0[d0[i]], 1)] = s0[i]; return; }
    i -= E_GP;
    if (i < E_MP) { e1[atomicAdd(&u1[d1[i]], 1)] = s1[i]; return; }
    i -= E_MP;
    if (i < E_PG) { e2[atomicAdd(&u2[d2[i]], 1)] = s2[i]; return; }
    i -= E_PG;
    if (i < E_PM) e3[atomicAdd(&u3[d3[i]], 1)] = s3[i];
}

// ---------------------------------------------------------------------------
// HGT edge attention core v9 — v6 structure (gathers, prefetch shadow,
// unconditional online softmax) with phase-1 dot on v_dot2_f32_bf16.
__device__ __forceinline__ void edge_seg_v9(
    const bf16p2* __restrict__ qd,        // this lane's 16 Q' dims as 8 bf16 pairs
    float* __restrict__ sS,               // wave's 64-entry score LDS
    float2* __restrict__ wssh,            // wave's 64-entry {w,src} LDS
    const int* __restrict__ es, int i0, int i1,
    const ushort_t* __restrict__ Kt, const ushort_t* __restrict__ Vt,
    float pscale, int lane, int koff,
    float& m, float& plsum, float2& acc)
{
    if (i0 >= i1) return;
    const int seg = lane & 3, eidx = lane >> 2;
    const int epar = lane >> 5;
    const int dpair = (lane & 31) << 1;
    const int kbase_off = koff + (seg << 3);   // ushort offset of this lane's slice

    bool valid = (i0 + lane) < i1;
    int sidx = valid ? es[i0 + lane] : 0;
    uint4 kv[8];
#pragma unroll
    for (int p = 0; p < 4; p++) {
        const int sp = __shfl(sidx, (p << 4) + eidx);
        const ushort_t* kr = Kt + ((size_t)sp << 8) + kbase_off;
        kv[2 * p]     = *(const uint4*)(kr);
        kv[2 * p + 1] = *(const uint4*)(kr + 32);
    }

    for (int c = i0; c < i1; c += 64) {
        const int e2 = c + 64 + lane;
        const bool valid2 = e2 < i1;
        const int sidx2 = valid2 ? es[e2] : 0;

        // ---- phase 1: 16-dim partial dots via v_dot2_f32_bf16 ----
#pragma unroll
        for (int p = 0; p < 4; p++) {
            const uint4 k0 = kv[2 * p], k1 = kv[2 * p + 1];
            float dp = 0.f;
            dp = __builtin_amdgcn_fdot2_f32_bf16(asbf2(k0.x), qd[0], dp, false);
            dp = __builtin_amdgcn_fdot2_f32_bf16(asbf2(k0.y), qd[1], dp, false);
            dp = __builtin_amdgcn_fdot2_f32_bf16(asbf2(k0.z), qd[2], dp, false);
            dp = __builtin_amdgcn_fdot2_f32_bf16(asbf2(k0.w), qd[3], dp, false);
            dp = __builtin_amdgcn_fdot2_f32_bf16(asbf2(k1.x), qd[4], dp, false);
            dp = __builtin_amdgcn_fdot2_f32_bf16(asbf2(k1.y), qd[5], dp, false);
            dp = __builtin_amdgcn_fdot2_f32_bf16(asbf2(k1.z), qd[6], dp, false);
            dp = __builtin_amdgcn_fdot2_f32_bf16(asbf2(k1.w), qd[7], dp, false);
            dp += __shfl_xor(dp, 1);
            dp += __shfl_xor(dp, 2);
            if (seg == 0) sS[(p << 4) + eidx] = dp;
        }
        // ---- prefetch next chunk's K (latency hides under phases 2-3) ----
#pragma unroll
        for (int p = 0; p < 4; p++) {
            const int sp = __shfl(sidx2, (p << 4) + eidx);
            const ushort_t* kr = Kt + ((size_t)sp << 8) + kbase_off;
            kv[2 * p]     = *(const uint4*)(kr);
            kv[2 * p + 1] = *(const uint4*)(kr + 32);
        }

        const float a = valid ? sS[lane] * pscale : -INFINITY;

        // ---- phase 2: chunk max + online rescale ----
        float cm = a;
#pragma unroll
        for (int o = 32; o; o >>= 1) cm = fmaxf(cm, __shfl_xor(cm, o));
        const float mn = fmaxf(m, cm);
        const float sc = (m == -INFINITY) ? 0.f : expf(m - mn);
        const float w = valid ? expf(a - mn) : 0.f;
        plsum = plsum * sc + w;
        m = mn;
        wssh[lane] = make_float2(w, __int_as_float(sidx));

        // ---- phase 3: batched coalesced V accumulate ----
        acc.x *= sc; acc.y *= sc;
        float2 aE = make_float2(0.f, 0.f), aO = make_float2(0.f, 0.f);
#pragma unroll
        for (int b = 0; b < 64; b += 16) {
            float2 we[8];
            unsigned vv[8];
#pragma unroll
            for (int j = 0; j < 8; j++) we[j] = wssh[b + (j << 1) + epar];
#pragma unroll
            for (int j = 0; j < 8; j++) {
                const int sj = __float_as_int(we[j].y);
                vv[j] = *(const unsigned*)(Vt + (((size_t)sj) << 8) + koff + dpair);
            }
#pragma unroll
            for (int j = 0; j < 8; j++) {
                const float wj = we[j].x;
                if (j & 1) { aO.x = fmaf(wj, bflo(vv[j]), aO.x);
                             aO.y = fmaf(wj, bfhi(vv[j]), aO.y); }
                else       { aE.x = fmaf(wj, bflo(vv[j]), aE.x);
                             aE.y = fmaf(wj, bfhi(vv[j]), aE.y); }
            }
        }
        acc.x += aE.x + aO.x;
        acc.y += aE.y + aO.y;

        valid = valid2; sidx = sidx2;
    }
}

// ---------------------------------------------------------------------------
// Edge attention: ONE block per (node, relation) item — dispatch-order phase
// locality keeps each relation's K/V table hot in per-XCD L2 (grid-striding
// measured 2.6x more HBM fetch — round 14). 4 waves = 4 heads, NO barriers.
__global__ __launch_bounds__(256) void edge_attn_v9(
    const float* __restrict__ QpDA, const float* __restrict__ QpDB,
    const float* __restrict__ QpS1, const float* __restrict__ QpS2,
    const int* __restrict__ offGP, const int* __restrict__ esGP,
    const int* __restrict__ offMP, const int* __restrict__ esMP,
    const int* __restrict__ offPG, const int* __restrict__ esPG,
    const int* __restrict__ offPM, const int* __restrict__ esPM,
    const ushort_t* __restrict__ K0t, const ushort_t* __restrict__ V0t,
    const ushort_t* __restrict__ K1t, const ushort_t* __restrict__ V1t,
    const ushort_t* __restrict__ K2t, const ushort_t* __restrict__ V2t,
    const float* __restrict__ prel,
    float* __restrict__ accD, float* __restrict__ mlD,
    ushort_t* __restrict__ out1, ushort_t* __restrict__ out2)
{
    __shared__ float sS[NHEAD][64];
    __shared__ float2 wssh[NHEAD][64];
    const int b = blockIdx.x, tid = threadIdx.x, lane = tid & 63, h = tid >> 6;
    const int koff = h << 6, seg = lane & 3;

    const float* Qp; const int* off; const int* es;
    const ushort_t* Kt; const ushort_t* Vt;
    int node, r, dual = -1;
    if (b < N0)            { node = b;            Qp = QpDA; off = offGP; es = esGP; Kt = K1t; Vt = V1t; r = 1; dual = 0; }
    else if (b < 2 * N0)   { node = b - N0;       Qp = QpDB; off = offMP; es = esMP; Kt = K2t; Vt = V2t; r = 3; dual = 1; }
    else if (b < 2 * N0 + N1) { node = b - 2 * N0;      Qp = QpS1; off = offPG; es = esPG; Kt = K0t; Vt = V0t; r = 0; }
    else                      { node = b - 2 * N0 - N1; Qp = QpS2; off = offPM; es = esPM; Kt = K0t; Vt = V0t; r = 2; }

    const float* qrow = Qp + (size_t)node * HIDF + koff;
    float4 qv[4];
    qv[0] = *(const float4*)(qrow + (seg << 3));
    qv[1] = *(const float4*)(qrow + (seg << 3) + 4);
    qv[2] = *(const float4*)(qrow + 32 + (seg << 3));
    qv[3] = *(const float4*)(qrow + 32 + (seg << 3) + 4);
    bf16p2 qd[8];
#pragma unroll
    for (int i = 0; i < 4; i++) {
        const unsigned p0 = (unsigned)f2bf(qv[i].x) | ((unsigned)f2bf(qv[i].y) << 16);
        const unsigned p1 = (unsigned)f2bf(qv[i].z) | ((unsigned)f2bf(qv[i].w) << 16);
        qd[2 * i]     = asbf2(p0);
        qd[2 * i + 1] = asbf2(p1);
    }
    const float ps = prel[(r << 2) + h] * ATT_SCALE;
    float m = -INFINITY, plsum = 0.f;
    float2 acc = make_float2(0.f, 0.f);
    edge_seg_v9(qd, sS[h], wssh[h], es, off[node], off[node + 1],
                Kt, Vt, ps, lane, koff, m, plsum, acc);
    acc.x += __shfl_xor(acc.x, 32);
    acc.y += __shfl_xor(acc.y, 32);
    float l = plsum;
#pragma unroll
    for (int o = 32; o; o >>= 1) l += __shfl_xor(l, o);

    if (dual >= 0) {
        if (lane < 32)
            *(float2*)(accD + ((size_t)(dual * N0 + node)) * HIDF + koff + ((lane & 31) << 1))
                = acc;
        if (lane == 0) {
            mlD[((size_t)(dual * N0 + node)) * 8 + h * 2 + 0] = m;
            mlD[((size_t)(dual * N0 + node)) * 8 + h * 2 + 1] = l;
        }
    } else {
        const float inv = (l > 0.f) ? 1.f / l : 0.f;
        ushort_t* out = (r == 0) ? out1 : out2;
        if (lane < 32) {
            const unsigned pk = (unsigned)f2bf(acc.x * inv) | ((unsigned)f2bf(acc.y * inv) << 16);
            *(unsigned*)(out + (size_t)node * HIDF + koff + ((lane & 31) << 1)) = pk;
        }
    }
}

// Exact flash-combine of the two participant relations -> bf16 [N0][512].
__global__ __launch_bounds__(256) void combine0_kernel(
    const float* __restrict__ accD, const float* __restrict__ mlD,
    ushort_t* __restrict__ out0)
{
    const int node = blockIdx.x, col = threadIdx.x;   // col in [0,256)
    const int h = col >> 6;
    const float m0 = mlD[((size_t)node) * 8 + h * 2 + 0];
    const float l0 = mlD[((size_t)node) * 8 + h * 2 + 1];
    const float m1 = mlD[((size_t)(N0 + node)) * 8 + h * 2 + 0];
    const float l1 = mlD[((size_t)(N0 + node)) * 8 + h * 2 + 1];
    const float M = fmaxf(m0, m1);
    const float s0 = (m0 == -INFINITY) ? 0.f : expf(m0 - M);
    const float s1 = (m1 == -INFINITY) ? 0.f : expf(m1 - M);
    const float L = l0 * s0 + l1 * s1;
    const float f0 = (L > 0.f) ? s0 / L : 0.f;
    const float f1 = (L > 0.f) ? s1 / L : 0.f;
    const float a0 = accD[((size_t)node) * HIDF + col];
    const float a1 = accD[((size_t)(N0 + node)) * HIDF + col];
    out0[(size_t)node * 512 + col]       = f2bf(a0 * f0);
    out0[(size_t)node * 512 + 256 + col] = f2bf(a1 * f1);
}

// ---------------------------------------------------------------------------
// Flash cross-attention v3: 32 q-rows per block (two A fragments per wave,
// K/V registers reused across both -> 2x arithmetic intensity per K byte).
struct FlashDesc { const ushort_t* qh; const ushort_t* kh; const ushort_t* vT;
                   ushort_t* O; int Nq; };
template <int NF> struct FlashDescArr { FlashDesc d[NF]; };

template <int NF>
__global__ __launch_bounds__(256) void flash_ca(FlashDescArr<NF> P, int Nk)
{
    const FlashDesc g = P.d[blockIdx.z];
    const int q0 = blockIdx.x << 5;            // 32 q-rows per block
    if (q0 >= g.Nq) return;
    __shared__ float mS[4][32], lS[4][32];
    __shared__ __align__(16) char uS[18432];   // union: Pl[4][32][72] / oS[4][16][64]
    ushort_t (*Pl)[32][72] = (ushort_t (*)[32][72])uS;
    float    (*oS)[16][64] = (float (*)[16][64])uS;
    const int head = blockIdx.y;
    const int tid = threadIdx.x, wave = tid >> 6, lane = tid & 63;
    const int l15 = lane & 15, lg = lane >> 4;
    const int Nq = g.Nq;

    bf16x8 qa[2][2];
    {
        const ushort_t* qb0 = g.qh + ((size_t)head * Nq + q0 + l15) * 64 + (lg << 3);
        qa[0][0] = *(const bf16x8*)qb0;
        qa[0][1] = *(const bf16x8*)(qb0 + 32);
        qa[1][0] = *(const bf16x8*)(qb0 + 16 * 64);
        qa[1][1] = *(const bf16x8*)(qb0 + 16 * 64 + 32);
    }
    const ushort_t* kbase = g.kh + (size_t)head * Nk * 64;
    const ushort_t* vbase = g.vT + (size_t)head * 64 * Nk;
    const int kchunk = Nk >> 2;
    const int kbeg = wave * kchunk, kend = kbeg + kchunk;

    f32x4 o[2][4] = {};
    float m[2][4]     = {{-INFINITY,-INFINITY,-INFINITY,-INFINITY},
                         {-INFINITY,-INFINITY,-INFINITY,-INFINITY}};
    float plsum[2][4] = {};

    bf16x8 ka[8];
    {
        const ushort_t* krow = kbase + ((size_t)(kbeg + l15)) * 64 + (lg << 3);
#pragma unroll
        for (int ct = 0; ct < 4; ct++) {
            ka[ct]     = *(const bf16x8*)(krow + (ct << 10));
            ka[4 + ct] = *(const bf16x8*)(krow + (ct << 10) + 32);
        }
    }

    for (int k0 = kbeg; k0 < kend; k0 += 64) {
        bf16x8 vv[8];
        const ushort_t* vrow = vbase + (size_t)l15 * Nk + k0 + (lg << 3);
#pragma unroll
        for (int vt = 0; vt < 4; vt++) {
            vv[vt]     = *(const bf16x8*)(vrow + (size_t)(vt << 4) * Nk);
            vv[4 + vt] = *(const bf16x8*)(vrow + (size_t)(vt << 4) * Nk + 32);
        }
        f32x4 s[2][4] = {};
#pragma unroll
        for (int g2 = 0; g2 < 2; g2++)
#pragma unroll
            for (int ct = 0; ct < 4; ct++)
                s[g2][ct] = __builtin_amdgcn_mfma_f32_16x16x32_bf16(qa[g2][0], ka[ct], s[g2][ct], 0, 0, 0);
#pragma unroll
        for (int g2 = 0; g2 < 2; g2++)
#pragma unroll
            for (int ct = 0; ct < 4; ct++)
                s[g2][ct] = __builtin_amdgcn_mfma_f32_16x16x32_bf16(qa[g2][1], ka[4 + ct], s[g2][ct], 0, 0, 0);
        if (k0 + 64 < kend) {
            const ushort_t* krow2 = kbase + ((size_t)(k0 + 64 + l15)) * 64 + (lg << 3);
#pragma unroll
            for (int ct = 0; ct < 4; ct++) {
                ka[ct]     = *(const bf16x8*)(krow2 + (ct << 10));
                ka[4 + ct] = *(const bf16x8*)(krow2 + (ct << 10) + 32);
            }
        }
        float tm[2][4];
        bool need = false;
#pragma unroll
        for (int g2 = 0; g2 < 2; g2++)
#pragma unroll
            for (int r = 0; r < 4; r++) {
                tm[g2][r] = fmaxf(fmaxf(s[g2][0][r], s[g2][1][r]),
                                  fmaxf(s[g2][2][r], s[g2][3][r]));
                need = need || (tm[g2][r] > m[g2][r] + 11.54f);
            }
        if (__any(need)) {
#pragma unroll
            for (int off = 1; off <= 8; off <<= 1)
#pragma unroll
                for (int g2 = 0; g2 < 2; g2++)
#pragma unroll
                    for (int r = 0; r < 4; r++)
                        tm[g2][r] = fmaxf(tm[g2][r], __shfl_xor(tm[g2][r], off));
#pragma unroll
            for (int g2 = 0; g2 < 2; g2++)
#pragma unroll
                for (int r = 0; r < 4; r++) {
                    const float mn = fmaxf(m[g2][r], tm[g2][r]);
                    const float sc = exp2f(m[g2][r] - mn);
                    m[g2][r] = mn;
                    plsum[g2][r] *= sc;
#pragma unroll
                    for (int vt = 0; vt < 4; vt++) o[g2][vt][r] *= sc;
                }
        }
#pragma unroll
        for (int g2 = 0; g2 < 2; g2++)
#pragma unroll
            for (int ct = 0; ct < 4; ct++)
#pragma unroll
                for (int r = 0; r < 4; r++) {
                    const float p = exp2f(s[g2][ct][r] - m[g2][r]);
                    plsum[g2][r] += p;
                    Pl[wave][(g2 << 4) + (lg << 2) + r][(ct << 4) + l15] = f2bf(p);
                }
        const bf16x8 pa00 = *(const bf16x8*)&Pl[wave][l15][lg << 3];
        const bf16x8 pa01 = *(const bf16x8*)&Pl[wave][l15][32 + (lg << 3)];
        const bf16x8 pa10 = *(const bf16x8*)&Pl[wave][16 + l15][lg << 3];
        const bf16x8 pa11 = *(const bf16x8*)&Pl[wave][16 + l15][32 + (lg << 3)];
#pragma unroll
        for (int vt = 0; vt < 4; vt++) {
            o[0][vt] = __builtin_amdgcn_mfma_f32_16x16x32_bf16(pa00, vv[vt], o[0][vt], 0, 0, 0);
            o[1][vt] = __builtin_amdgcn_mfma_f32_16x16x32_bf16(pa10, vv[vt], o[1][vt], 0, 0, 0);
        }
#pragma unroll
        for (int vt = 0; vt < 4; vt++) {
            o[0][vt] = __builtin_amdgcn_mfma_f32_16x16x32_bf16(pa01, vv[4 + vt], o[0][vt], 0, 0, 0);
            o[1][vt] = __builtin_amdgcn_mfma_f32_16x16x32_bf16(pa11, vv[4 + vt], o[1][vt], 0, 0, 0);
        }
    }
#pragma unroll
    for (int off = 1; off <= 8; off <<= 1)
#pragma unroll
        for (int g2 = 0; g2 < 2; g2++)
#pragma unroll
            for (int r = 0; r < 4; r++)
                plsum[g2][r] += __shfl_xor(plsum[g2][r], off);
    if (l15 == 0) {
#pragma unroll
        for (int g2 = 0; g2 < 2; g2++)
#pragma unroll
            for (int r = 0; r < 4; r++) {
                mS[wave][(g2 << 4) + (lg << 2) + r] = m[g2][r];
                lS[wave][(g2 << 4) + (lg << 2) + r] = plsum[g2][r];
            }
    }
    __syncthreads();
#pragma unroll
    for (int g2 = 0; g2 < 2; g2++) {
        float fac[4];
#pragma unroll
        for (int r = 0; r < 4; r++) {
            const int grow = (g2 << 4) + (lg << 2) + r;
            const float ms = fmaxf(fmaxf(mS[0][grow], mS[1][grow]),
                                   fmaxf(mS[2][grow], mS[3][grow]));
            fac[r] = exp2f(m[g2][r] - ms);
        }
        __syncthreads();
#pragma unroll
        for (int vt = 0; vt < 4; vt++)
#pragma unroll
            for (int r = 0; r < 4; r++)
                oS[wave][(lg << 2) + r][(vt << 4) + l15] = o[g2][vt][r] * fac[r];
        __syncthreads();
        for (int i = tid; i < 1024; i += 256) {
            const int row = i >> 6, d = i & 63;
            const int grow = (g2 << 4) + row;
            const float m0 = mS[0][grow], m1 = mS[1][grow], m2 = mS[2][grow], m3 = mS[3][grow];
            const float ms = fmaxf(fmaxf(m0, m1), fmaxf(m2, m3));
            const float L = lS[0][grow] * exp2f(m0 - ms) + lS[1][grow] * exp2f(m1 - ms)
                          + lS[2][grow] * exp2f(m2 - ms) + lS[3][grow] * exp2f(m3 - ms);
            const float val = oS[0][row][d] + oS[1][row][d] + oS[2][row][d] + oS[3][row][d];
            g.O[(size_t)(q0 + grow) * HIDF + (head << 6) + d] = f2bf(val / L);
        }
    }
}

// ---------------------------------------------------------------------------
// Fused residual + LayerNorm + exact GELU over ALL node types in one launch.
__global__ __launch_bounds__(256) void ln_gelu_all(
    float* __restrict__ h, ushort_t* __restrict__ hb16, const float* __restrict__ hg,
    const float* __restrict__ lng, const float* __restrict__ lnb)
{
    __shared__ float t4[4];
    const int row = blockIdx.x, tid = threadIdx.x, lane = tid & 63, w = tid >> 6;
    const int t = (row >= N0) + (row >= N0 + N1);
    const size_t idx = (size_t)row * HIDF + tid;
    const float x = h[idx] + hg[idx];
    float v = x;
#pragma unroll
    for (int o = 32; o; o >>= 1) v += __shfl_xor(v, o);
    if (lane == 0) t4[w] = v;
    __syncthreads();
    const float mean = (t4[0] + t4[1] + t4[2] + t4[3]) * (1.f / 256.f);
    __syncthreads();
    const float d = x - mean;
    v = d * d;
#pragma unroll
    for (int o = 32; o; o >>= 1) v += __shfl_xor(v, o);
    if (lane == 0) t4[w] = v;
    __syncthreads();
    const float var = (t4[0] + t4[1] + t4[2] + t4[3]) * (1.f / 256.f);
    const float y = gelu_exact(d * rsqrtf(var + 1e-5f) * lng[t * HIDF + tid] + lnb[t * HIDF + tid]);
    h[idx] = y;
    hb16[idx] = f2bf(y);
}

// ---------------------------------------------------------------------------
extern "C" void kernel_launch(void* const* d_in, const int* in_sizes, int n_in,
                              void* d_out, int out_size, void* d_ws, size_t ws_size,
                              hipStream_t stream)
{
    (void)in_sizes; (void)n_in; (void)out_size; (void)ws_size;
    const float* x_p   = (const float*)d_in[0];
    const float* x_g   = (const float*)d_in[1];
    const float* x_m   = (const float*)d_in[2];
    const int*  src_pg = (const int*)d_in[3];
    const int*  dst_pg = (const int*)d_in[4];
    const int*  src_gp = (const int*)d_in[5];
    const int*  dst_gp = (const int*)d_in[6];
    const int*  src_pm = (const int*)d_in[7];
    const int*  dst_pm = (const int*)d_in[8];
    const int*  src_mp = (const int*)d_in[9];
    const int*  dst_mp = (const int*)d_in[10];
    const float* Win_p = (const float*)d_in[11];
    const float* bin_p = (const float*)d_in[12];
    const float* Win_g = (const float*)d_in[13];
    const float* bin_g = (const float*)d_in[14];
    const float* Win_m = (const float*)d_in[15];
    const float* bin_m = (const float*)d_in[16];
    const float* kw    = (const float*)d_in[17];
    const float* qw    = (const float*)d_in[18];
    const float* vw    = (const float*)d_in[19];
    const float* aw    = (const float*)d_in[20];
    const float* kb    = (const float*)d_in[21];
    const float* qb    = (const float*)d_in[22];
    const float* vb    = (const float*)d_in[23];
    const float* ab    = (const float*)d_in[24];
    const float* skip  = (const float*)d_in[25];
    const float* a_rel = (const float*)d_in[26];
    const float* m_rel = (const float*)d_in[27];
    const float* p_rel = (const float*)d_in[28];
    const float* ca_qw = (const float*)d_in[29];
    const float* ca_kw = (const float*)d_in[30];
    const float* ca_vw = (const float*)d_in[31];
    const float* ca_ow = (const float*)d_in[32];
    const float* ca_qb = (const float*)d_in[33];
    const float* ca_kb = (const float*)d_in[34];
    const float* ca_vb = (const float*)d_in[35];
    const float* ca_ob = (const float*)d_in[36];
    const float* ln_g  = (const float*)d_in[37];
    const float* ln_b  = (const float*)d_in[38];
    const float* outw  = (const float*)d_in[39];
    const float* outb  = (const float*)d_in[40];
    float* dout = (float*)d_out;

    // ---- workspace carve-up ----
    float* Wp = (float*)d_ws;
    size_t cursz = 0;
    auto alloc = [&](size_t n) -> float* {
        float* p = Wp + cursz; cursz += (n + 63) & ~(size_t)63; return p;
    };
    const size_t NT = N0 + N1 + N2;               // 9216
    float* h0  = alloc((size_t)N0 * HIDF);
    float* h1  = alloc((size_t)N1 * HIDF);
    float* h2  = alloc((size_t)N2 * HIDF);
    float* hg0 = alloc((size_t)N0 * HIDF);
    float* hg1 = alloc((size_t)N1 * HIDF);
    float* hg2 = alloc((size_t)N2 * HIDF);
    ushort_t* hb  = (ushort_t*)alloc(NT * HIDF / 2);
    ushort_t* K16 = (ushort_t*)alloc(NT * HIDF / 2);
    ushort_t* V16 = (ushort_t*)alloc(NT * HIDF / 2);
    ushort_t* K16_0 = K16, *K16_1 = K16 + (size_t)N0 * HIDF, *K16_2 = K16 + (size_t)(N0 + N1) * HIDF;
    ushort_t* V16_0 = V16, *V16_1 = V16 + (size_t)N0 * HIDF, *V16_2 = V16 + (size_t)(N0 + N1) * HIDF;
    float* QpPool  = alloc((size_t)(N1 + N0 + N2 + N0) * HIDF);   // fp32 Q' x4
    float* Qp0 = QpPool;
    float* Qp1 = Qp0 + (size_t)N1 * HIDF;
    float* Qp2 = Qp1 + (size_t)N0 * HIDF;
    float* Qp3 = Qp2 + (size_t)N2 * HIDF;
    float* accD = alloc((size_t)2 * N0 * HIDF);                   // dual fp32 partials
    float* mlD  = alloc((size_t)2 * N0 * 8);                      // dual (m,l) per head
    ushort_t* part0b = (ushort_t*)alloc((size_t)N0 * 512 / 2);    // [N0][512] bf16
    ushort_t* part1b = (ushort_t*)alloc((size_t)N1 * HIDF / 2);
    ushort_t* part2b = (ushort_t*)alloc((size_t)N2 * HIDF / 2);
    ushort_t* aggb16 = (ushort_t*)alloc(NT * HIDF / 2);
    ushort_t* qhA   = (ushort_t*)alloc((size_t)N1 * HIDF / 2);
    ushort_t* qhB   = (ushort_t*)alloc((size_t)N2 * HIDF / 2);
    ushort_t* khA   = (ushort_t*)alloc((size_t)N0 * HIDF / 2);
    ushort_t* khB   = (ushort_t*)alloc((size_t)N0 * HIDF / 2);
    ushort_t* vTA   = (ushort_t*)alloc((size_t)N0 * HIDF / 2);
    ushort_t* vTB   = (ushort_t*)alloc((size_t)N0 * HIDF / 2);
    ushort_t* caobA = (ushort_t*)alloc((size_t)N1 * HIDF / 2);
    ushort_t* caobB = (ushort_t*)alloc((size_t)N2 * HIDF / 2);
    ushort_t* WT16 = (ushort_t*)alloc(2621440 / 2);               // transposed weights
    ushort_t* WqpT = (ushort_t*)alloc((size_t)8 * 65536 / 2);     // folded Q' weights
    float*    bqp  = alloc(8 * 256);                              // folded Q' biases
    ushort_t* WmT  = (ushort_t*)alloc((size_t)2 * 262144 / 2);    // expanded m_rel
    // bf16 x inputs alias QpPool (dead before layer loop)
    ushort_t* xb = (ushort_t*)QpPool;
    int* es_gp = (int*)alloc(E_GP);
    int* es_mp = (int*)alloc(E_MP);
    int* es_pg = (int*)alloc(E_PG);
    int* es_pm = (int*)alloc(E_PM);
    int* off_gp = (int*)alloc(N0 + 1);
    int* off_mp = (int*)alloc(N0 + 1);
    int* off_pg = (int*)alloc(N1 + 1);
    int* off_pm = (int*)alloc(N2 + 1);
    // contiguous cur arrays (zeroed inside preproc)
    int* cur_all = (int*)alloc(2 * N0 + N1 + N2);
    int* cur_gp = cur_all;
    int* cur_mp = cur_all + N0;
    int* cur_pg = cur_all + 2 * N0;
    int* cur_pm = cur_all + 2 * N0 + N1;

    // WT16 sub-offsets (ushort units)
    ushort_t* kwT    = WT16;
    ushort_t* vwT    = WT16 + 6 * 65536;
    ushort_t* awT    = WT16 + 12 * 65536;
    ushort_t* ca_qwT = WT16 + 18 * 65536;
    ushort_t* ca_kwT = WT16 + 20 * 65536;
    ushort_t* ca_vwT = WT16 + 22 * 65536;
    ushort_t* ca_owT = WT16 + 24 * 65536;
    ushort_t* outwT  = WT16 + 26 * 65536;
    ushort_t* WinTp  = outwT + 3 * 32768;
    ushort_t* WinTg  = WinTp + 256 * 512;
    ushort_t* WinTm  = WinTg + 256 * 768;

    // ---- ONE fused preprocessing launch: transW + qfold + mexpand + cast3
    //      + cur zeroing ----
    ushort_t* WmT_l[2][3];
    {
        PreprocArgs P;
        for (int i = 0; i < 6; i++) {
            P.T.d[i]      = { kw + (size_t)i * 65536, kwT + (size_t)i * 65536, 256, 256 };
            P.T.d[6 + i]  = { vw + (size_t)i * 65536, vwT + (size_t)i * 65536, 256, 256 };
            P.T.d[12 + i] = { aw + (size_t)i * 65536, awT + (size_t)i * 65536, 256, 256 };
        }
        for (int c = 0; c < 2; c++) {
            P.T.d[18 + c] = { ca_qw + (size_t)c * 65536, ca_qwT + (size_t)c * 65536, 256, 256 };
            P.T.d[20 + c] = { ca_kw + (size_t)c * 65536, ca_kwT + (size_t)c * 65536, 256, 256 };
            P.T.d[22 + c] = { ca_vw + (size_t)c * 65536, ca_vwT + (size_t)c * 65536, 256, 256 };
            P.T.d[24 + c] = { ca_ow + (size_t)c * 65536, ca_owT + (size_t)c * 65536, 256, 256 };
        }
        for (int t = 0; t < 3; t++)
            P.T.d[26 + t] = { outw + (size_t)t * 32768, outwT + (size_t)t * 32768, 256, 128 };
        P.T.d[29] = { Win_p, WinTp, 512, 256 };
        P.T.d[30] = { Win_g, WinTg, 768, 256 };
        P.T.d[31] = { Win_m, WinTm, 384, 256 };

        const int dstt[4] = { 1, 0, 2, 0 };
        for (int l = 0; l < 2; l++)
            for (int r = 0; r < 4; r++) {
                const int z = l * 4 + r, dt = dstt[r];
                P.Q.d[z] = { a_rel + (size_t)z * 16384,
                             qw + (size_t)(l * 3 + dt) * 65536,
                             qb + (size_t)(l * 3 + dt) * 256,
                             WqpT + (size_t)z * 65536, bqp + (size_t)z * 256 };
            }

        for (int l = 0; l < 2; l++) {
            ushort_t* base = WmT + (size_t)l * 262144;
            WmT_l[l][0] = base;
            WmT_l[l][1] = base + 131072;
            WmT_l[l][2] = base + 196608;
            const float* mr = m_rel + (size_t)l * 4 * 16384;
            P.X.d[l * 3 + 0] = { mr + 1 * 16384, mr + 3 * 16384, WmT_l[l][0], 512 };
            P.X.d[l * 3 + 1] = { mr + 0 * 16384, nullptr,        WmT_l[l][1], 256 };
            P.X.d[l * 3 + 2] = { mr + 2 * 16384, nullptr,        WmT_l[l][2], 256 };
        }
        P.xa = x_p; P.xg = x_g; P.xm = x_m; P.xb = xb;
        P.cur_all = cur_all;
        preproc_kernel<<<PB_Z, 256, 0, stream>>>(P);
    }

    // ---- counting-sort edges by destination (3 more launches) ----
    count4_kernel<<<(E_TOT + 255) / 256, 256, 0, stream>>>(
        dst_gp, dst_mp, dst_pg, dst_pm, cur_gp, cur_mp, cur_pg, cur_pm);
    {
        ScanDesc s0 = { cur_gp, N0, off_gp };
        ScanDesc s1 = { cur_mp, N0, off_mp };
        ScanDesc s2 = { cur_pg, N1, off_pg };
        ScanDesc s3 = { cur_pm, N2, off_pm };
        scan4_kernel<<<4, 256, 0, stream>>>(s0, s1, s2, s3);
    }
    scatter4_kernel<<<(E_TOT + 255) / 256, 256, 0, stream>>>(
        src_gp, dst_gp, cur_gp, es_gp,
        src_mp, dst_mp, cur_mp, es_mp,
        src_pg, dst_pg, cur_pg, es_pg,
        src_pm, dst_pm, cur_pm, es_pm);

    float* hgptr[3] = { hg0, hg1, hg2 };
    float* hptr[3]  = { h0, h1, h2 };
    const int Ns[3] = { N0, N1, N2 };
    const size_t hoff[3] = { 0, (size_t)N0 * HIDF, (size_t)(N0 + N1) * HIDF };

    // ---- input projections (STOREBOTH: h fp32 + hb bf16) ----
    const size_t xoff1 = (size_t)N0 * 512, xoff2 = xoff1 + (size_t)N1 * 768;
    {
        MGemmDescArr<3> D;
        D.d[0] = { xb,         WinTp, h0, bin_p, nullptr, hb + hoff[0], N0, 512, M_STOREBOTH, 0.f };
        D.d[1] = { xb + xoff1, WinTg, h1, bin_g, nullptr, hb + hoff[1], N1, 768, M_STOREBOTH, 0.f };
        D.d[2] = { xb + xoff2, WinTm, h2, bin_m, nullptr, hb + hoff[2], N2, 384, M_STOREBOTH, 0.f };
        gemm_mfma<3><<<dim3(4, 32, 3), 256, 0, stream>>>(D, HIDF);
    }

    for (int l = 0; l < 2; l++) {
        // Q' (folded a_rel, x4) + K/V projections (x6) in ONE launch
        {
            ushort_t* Kp[3] = { K16_0, K16_1, K16_2 };
            ushort_t* Vp[3] = { V16_0, V16_1, V16_2 };
            const size_t zb = (size_t)l * 4;
            MGemmDescArr<10> D;
            D.d[0] = { hb + hoff[1], WqpT + (zb + 0) * 65536, Qp0, bqp + (zb + 0) * 256, nullptr, nullptr, N1, HIDF, M_STORE, 0.f };
            D.d[1] = { hb + hoff[0], WqpT + (zb + 1) * 65536, Qp1, bqp + (zb + 1) * 256, nullptr, nullptr, N0, HIDF, M_STORE, 0.f };
            D.d[2] = { hb + hoff[2], WqpT + (zb + 2) * 65536, Qp2, bqp + (zb + 2) * 256, nullptr, nullptr, N2, HIDF, M_STORE, 0.f };
            D.d[3] = { hb + hoff[0], WqpT + (zb + 3) * 65536, Qp3, bqp + (zb + 3) * 256, nullptr, nullptr, N0, HIDF, M_STORE, 0.f };
            for (int t = 0; t < 3; t++) {
                D.d[4 + t] = { hb + hoff[t], kwT + (size_t)(l * 3 + t) * 65536, Kp[t],
                               kb + (size_t)(l * 3 + t) * HIDF, nullptr, nullptr, Ns[t], HIDF, M_B16, 0.f };
                D.d[7 + t] = { hb + hoff[t], vwT + (size_t)(l * 3 + t) * 65536, Vp[t],
                               vb + (size_t)(l * 3 + t) * HIDF, nullptr, nullptr, Ns[t], HIDF, M_B16, 0.f };
            }
            gemm_mfma<10><<<dim3(4, 32, 10), 256, 0, stream>>>(D, HIDF);
        }
        // segment-softmax edge attention: one block per (node, relation)
        const float* prl = p_rel + (size_t)l * 16;
        edge_attn_v9<<<EDGE_ITEMS, 256, 0, stream>>>(
            Qp1, Qp3, Qp0, Qp2,
            off_gp, es_gp, off_mp, es_mp, off_pg, es_pg, off_pm, es_pm,
            K16_0, V16_0, K16_1, V16_1, K16_2, V16_2,
            prl, accD, mlD, part1b, part2b);
        combine0_kernel<<<N0, 256, 0, stream>>>(accD, mlD, part0b);
        // agg = gelu(sum_r partial_r @ m_rel[r]) -> bf16 (fused epilogue)
        {
            MGemmDescArr<3> D;
            D.d[0] = { part0b, WmT_l[l][0], aggb16 + hoff[0], nullptr, nullptr, nullptr, N0, 512, M_GELU_B16, 0.f };
            D.d[1] = { part1b, WmT_l[l][1], aggb16 + hoff[1], nullptr, nullptr, nullptr, N1, 256, M_GELU_B16, 0.f };
            D.d[2] = { part2b, WmT_l[l][2], aggb16 + hoff[2], nullptr, nullptr, nullptr, N2, 256, M_GELU_B16, 0.f };
            gemm_mfma<3><<<dim3(4, 32, 3), 256, 0, stream>>>(D, HIDF);
        }
        // hg-skip (x3) + CA projections (x6) in ONE launch (independent)
        {
            MGemmDescArr<9> D;
            for (int t = 0; t < 3; t++)
                D.d[t] = { aggb16 + hoff[t], awT + (size_t)(l * 3 + t) * 65536, hgptr[t],
                           ab + (size_t)(l * 3 + t) * HIDF, skip + l * 3 + t, hptr[t], Ns[t], HIDF, M_SKIP, 0.f };
            D.d[3] = { hb + hoff[1], ca_qwT + 0 * 65536, qhA, ca_qb + 0 * HIDF, nullptr, nullptr, N1, HIDF, M_SPLITQ, ATT_SCALE * LOG2E };
            D.d[4] = { hb + hoff[0], ca_kwT + 0 * 65536, khA, ca_kb + 0 * HIDF, nullptr, nullptr, N0, HIDF, M_SPLITQ, 1.0f };
            D.d[5] = { hb + hoff[0], ca_vwT + 0 * 65536, vTA, ca_vb + 0 * HIDF, nullptr, nullptr, N0, HIDF, M_VT, 0.f };
            D.d[6] = { hb + hoff[2], ca_qwT + 1 * 65536, qhB, ca_qb + 1 * HIDF, nullptr, nullptr, N2, HIDF, M_SPLITQ, ATT_SCALE * LOG2E };
            D.d[7] = { hb + hoff[0], ca_kwT + 1 * 65536, khB, ca_kb + 1 * HIDF, nullptr, nullptr, N0, HIDF, M_SPLITQ, 1.0f };
            D.d[8] = { hb + hoff[0], ca_vwT + 1 * 65536, vTB, ca_vb + 1 * HIDF, nullptr, nullptr, N0, HIDF, M_VT, 0.f };
            gemm_mfma<9><<<dim3(4, 32, 9), 256, 0, stream>>>(D, HIDF);
        }
        // flash cross-attention (both feature types in one launch; 32 rows/blk)
        {
            FlashDescArr<2> F;
            F.d[0] = { qhA, khA, vTA, caobA, N1 };
            F.d[1] = { qhB, khB, vTB, caobB, N2 };
            flash_ca<2><<<dim3(N1 / 32, NHEAD, 2), 256, 0, stream>>>(F, N0);
        }
        // CA out-projection (ADD into hg)
        {
            MGemmDescArr<2> D;
            D.d[0] = { caobA, ca_owT + 0 * 65536, hg1, ca_ob + 0 * HIDF, nullptr, nullptr, N1, HIDF, M_ADD, 0.f };
            D.d[1] = { caobB, ca_owT + 1 * 65536, hg2, ca_ob + 1 * HIDF, nullptr, nullptr, N2, HIDF, M_ADD, 0.f };
            gemm_mfma<2><<<dim3(4, 32, 2), 256, 0, stream>>>(D, HIDF);
        }

        // h = gelu(LN(h + hg)) over all types; refreshes hb
        ln_gelu_all<<<(int)NT, 256, 0, stream>>>(h0, hb, hg0, ln_g, ln_b);
    }

    // ---- output projections (bf16 MFMA, N=128) ----
    {
        MGemmDescArr<3> D;
        D.d[0] = { hb + hoff[0], outwT + 0,     dout,                            outb,       nullptr, nullptr, N0, HIDF, M_STORE, 0.f };
        D.d[1] = { hb + hoff[1], outwT + 32768, dout + (size_t)N0 * OUTF,        outb + 128, nullptr, nullptr, N1, HIDF, M_STORE, 0.f };
        D.d[2] = { hb + hoff[2], outwT + 65536, dout + (size_t)(N0 + N1) * OUTF, outb + 256, nullptr, nullptr, N2, HIDF, M_STORE, 0.f };
        gemm_mfma<3><<<dim3(2, 32, 3), 256, 0, stream>>>(D, OUTF);
    }
}